// Round 8
// baseline (1129.621 us; speedup 1.0000x reference)
//
#include <hip/hip_runtime.h>
#include <hip/hip_bf16.h>

typedef __attribute__((ext_vector_type(8))) short short8;        // 8 bf16 = 4 VGPRs
typedef __attribute__((ext_vector_type(8))) unsigned short ushort8;
typedef __attribute__((ext_vector_type(4))) float f32x4;
typedef __attribute__((ext_vector_type(4))) unsigned int u32x4;
typedef __attribute__((ext_vector_type(2))) unsigned int u32x2;

#define DEV __device__ __forceinline__

DEV float gelu_f(float x) { return 0.5f * x * (1.f + erff(x * 0.70710678118654752440f)); }

DEV float bf2f(unsigned short s) {
  unsigned int t = ((unsigned int)s) << 16;
  float f; __builtin_memcpy(&f, &t, 4); return f;
}
DEV unsigned short f2bf(float f) {
  __hip_bfloat16 b = __float2bfloat16(f);
  unsigned short s; __builtin_memcpy(&s, &b, 2); return s;
}

// async global->LDS 16B/lane (dest = wave-uniform base + lane*16)
DEV void async_copy16(void* lds, const void* g) {
  __builtin_amdgcn_global_load_lds(
      (const __attribute__((address_space(1))) unsigned int*)g,
      (__attribute__((address_space(3))) unsigned int*)lds, 16, 0, 0);
}

// block-wide (256 thr) sum of two values; every thread gets the totals
DEV void block_reduce2(float& s, float& s2) {
  __shared__ float red[8];
  int tid = threadIdx.x;
#pragma unroll
  for (int o = 32; o > 0; o >>= 1) { s += __shfl_down(s, o); s2 += __shfl_down(s2, o); }
  if ((tid & 63) == 0) { red[tid >> 6] = s; red[4 + (tid >> 6)] = s2; }
  __syncthreads();
  s  = red[0] + red[1] + red[2] + red[3];
  s2 = red[4] + red[5] + red[6] + red[7];
}

// ---------------- weight fp32 -> bf16 ----------------
__global__ __launch_bounds__(256) void f2b_kernel(const float* __restrict__ in,
                                                  __hip_bfloat16* __restrict__ o, int n) {
  int i = blockIdx.x * 256 + threadIdx.x;
  if (i < n) o[i] = __float2bfloat16(in[i]);
}

// ---------------- mask -> bf16 padded [win][49][56] ----------------
__global__ __launch_bounds__(256) void maskb_kernel(const float* __restrict__ mask,
                                                    unsigned short* __restrict__ maskB) {
  int i = blockIdx.x * 256 + threadIdx.x;          // 256*49*56 = 702464 exactly
  int m = i % 56, rest = i / 56;
  int n = rest % 49, win = rest / 49;
  unsigned short v = 0;
  if (m < 49) v = f2bf(mask[((size_t)win * 49 + n) * 49 + m]);
  maskB[i] = v;
}

// ---------------- rpb -> bf16 padded [h][49][56] ----------------
__global__ __launch_bounds__(256) void rpbt_kernel(const float* __restrict__ rpb,
                                                   unsigned short* __restrict__ rpbT) {
  int i = blockIdx.x * 256 + threadIdx.x;          // 16*49*56 = 43904
  if (i >= 43904) return;
  int m = i % 56, rest = i / 56;
  int n = rest % 49, h = rest / 49;
  unsigned short v = 0;
  if (m < 49) {
    int rp = (n / 7 - m / 7 + 6) * 13 + (n % 7 - m % 7 + 6);
    v = f2bf(rpb[rp * 16 + h]);
  }
  rpbT[i] = v;
}

// ---------------- conv weight fragment table [co=16][160] (shared by all conv blocks) ----------------
__global__ __launch_bounds__(256) void cwt_kernel(const float* __restrict__ cw,
                                                  unsigned short* __restrict__ cwT) {
  int i = blockIdx.x * 256 + threadIdx.x;          // 2560
  if (i >= 2560) return;
  int co = i / 160, k = i % 160;
  unsigned short v = 0;
  if (k < 144) {
    int ci = k & 15, p = k >> 4;
    v = f2bf(cw[(co * 16 + ci) * 9 + p]);
  }
  cwT[i] = v;
}

// ---------------- LN1 + cyclic shift + window partition -> bf16 (wave-per-row) ----------------
__global__ __launch_bounds__(256) void ln1_window_kernel(
    const float* __restrict__ x, const float* __restrict__ w, const float* __restrict__ b,
    __hip_bfloat16* __restrict__ xw) {
  int tid = threadIdx.x;
  int wave = tid >> 6, lane = tid & 63;
  int t = blockIdx.x * 4 + wave;      // 0..25087
  int b_ = t / 49, n = t % 49;
  int bb = b_ >> 8, win = b_ & 255;
  int wi = win >> 4, wj = win & 15;
  int ii = n / 7, jj = n % 7;
  int sh = (wi * 7 + ii + 3) % 112;
  int sw = (wj * 7 + jj + 3) % 112;
  const float* row = x + ((size_t)bb * 12544 + sh * 112 + sw) * 512;
  f32x4 v0 = *reinterpret_cast<const f32x4*>(&row[lane * 8]);
  f32x4 v1 = *reinterpret_cast<const f32x4*>(&row[lane * 8 + 4]);
  float s = 0.f, s2 = 0.f;
#pragma unroll
  for (int j = 0; j < 4; j++) {
    s += v0[j] + v1[j];
    s2 += v0[j] * v0[j] + v1[j] * v1[j];
  }
#pragma unroll
  for (int o = 1; o < 64; o <<= 1) { s += __shfl_xor(s, o); s2 += __shfl_xor(s2, o); }
  float mu = s * (1.f / 512.f);
  float rstd = rsqrtf(s2 * (1.f / 512.f) - mu * mu + 1e-5f);
  f32x4 w0 = *reinterpret_cast<const f32x4*>(&w[lane * 8]);
  f32x4 w1 = *reinterpret_cast<const f32x4*>(&w[lane * 8 + 4]);
  f32x4 c0 = *reinterpret_cast<const f32x4*>(&b[lane * 8]);
  f32x4 c1 = *reinterpret_cast<const f32x4*>(&b[lane * 8 + 4]);
  ushort8 o8;
#pragma unroll
  for (int j = 0; j < 4; j++) {
    o8[j]     = f2bf((v0[j] - mu) * rstd * w0[j] + c0[j]);
    o8[4 + j] = f2bf((v1[j] - mu) * rstd * w1[j] + c1[j]);
  }
  *reinterpret_cast<ushort8*>((unsigned short*)xw + (size_t)t * 512 + lane * 8) = o8;
}

// ---------------- bf16 MFMA GEMM v2: double-buffered LDS (stage t+1 before compute t) ----
// EPI: 1 = bias -> bf16 store ; 2 = bias+gelu -> bf16 ; 3 = bias -> f32 +=
//      4 = merged qkv: col<512 -> q_bf (stride 512), col>=512 -> kv_bf (stride 1024)
// One __syncthreads per K-step (was two); next tile's global_load_lds overlap the MFMA
// phase, so the barrier drain only pays the latency remainder. 64KB LDS -> 2 blocks/CU
// (measured residency was ~1 anyway at 32KB).
// 1-D grid + bijective XCD swizzle (n fastest within an XCD chunk).
template <int EPI>
__global__ __launch_bounds__(256) void gemm_bt(
    const __hip_bfloat16* __restrict__ A, const __hip_bfloat16* __restrict__ B,
    const float* __restrict__ bias, float* __restrict__ outF,
    __hip_bfloat16* __restrict__ outB, int M, int N, int K) {
  __shared__ __align__(16) __hip_bfloat16 As[2][128 * 64];   // unpadded (global_load_lds layout)
  __shared__ __align__(16) __hip_bfloat16 Bs[2][128 * 64];
  int nn = N >> 7;
  int nblk = gridDim.x;
  int bid = blockIdx.x;
  int xcd = bid & 7, slot = bid >> 3;
  int q8 = nblk >> 3, r8 = nblk & 7;
  int base = xcd < r8 ? xcd * (q8 + 1) : r8 * (q8 + 1) + (xcd - r8) * q8;
  int lin = base + slot;              // bijective; n fastest
  int m0 = (lin / nn) << 7, n0 = (lin % nn) << 7;
  int tid = threadIdx.x;
  int wave = tid >> 6, lane = tid & 63;
  int wm = (wave & 1) * 64, wn = (wave >> 1) * 64;
  int lrow = lane & 15, kq = lane >> 4;
  int srow = lane >> 3, scol = (lane & 7) * 8;     // staging: 8 rows x 64 cols per wave-inst
  int rb = wave * 32;
  const __hip_bfloat16* Abase = A + (size_t)m0 * K;
  const __hip_bfloat16* Bbase = B + (size_t)n0 * K;
  // prologue: stage tile 0 into buffer 0
#pragma unroll
  for (int i = 0; i < 4; i++) {
    int row = rb + i * 8 + srow;
    async_copy16(&As[0][(rb + i * 8) * 64], &Abase[(size_t)row * K + scol]);
    async_copy16(&Bs[0][(rb + i * 8) * 64], &Bbase[(size_t)row * K + scol]);
  }
  __syncthreads();
  f32x4 acc[4][4] = {};
  int nk = K >> 6;
  for (int t = 0; t < nk; t++) {
    int cur = t & 1;
    if (t + 1 < nk) {
      int k0 = (t + 1) << 6;
#pragma unroll
      for (int i = 0; i < 4; i++) {
        int row = rb + i * 8 + srow;
        async_copy16(&As[cur ^ 1][(rb + i * 8) * 64], &Abase[(size_t)row * K + k0 + scol]);
        async_copy16(&Bs[cur ^ 1][(rb + i * 8) * 64], &Bbase[(size_t)row * K + k0 + scol]);
      }
    }
#pragma unroll
    for (int ks = 0; ks < 2; ks++) {
      short8 af[4], bf[4];
#pragma unroll
      for (int u = 0; u < 4; u++) {
        af[u] = *reinterpret_cast<const short8*>(&As[cur][(wm + u * 16 + lrow) * 64 + ks * 32 + kq * 8]);
        bf[u] = *reinterpret_cast<const short8*>(&Bs[cur][(wn + u * 16 + lrow) * 64 + ks * 32 + kq * 8]);
      }
#pragma unroll
      for (int tm = 0; tm < 4; tm++)
#pragma unroll
        for (int tn = 0; tn < 4; tn++)
          acc[tm][tn] = __builtin_amdgcn_mfma_f32_16x16x32_bf16(af[tm], bf[tn], acc[tm][tn], 0, 0, 0);
    }
    __syncthreads();   // drains stage(t+1) loads (overlapped with the MFMAs above) +
                       // guards buf[cur] reuse at t+2
  }
  // D: row=(lane>>4)*4+r, col=lane&15 (verified gfx950 C/D layout)
#pragma unroll
  for (int tm = 0; tm < 4; tm++) {
#pragma unroll
    for (int tn = 0; tn < 4; tn++) {
      int col = n0 + wn + tn * 16 + lrow;
      float bv = bias[col];
#pragma unroll
      for (int r = 0; r < 4; r++) {
        int row = m0 + wm + tm * 16 + kq * 4 + r;
        float v = acc[tm][tn][r] + bv;
        if (EPI == 4) {
          if (col < 512)
            ((unsigned short*)outB)[(size_t)row * 512 + col] = f2bf(v);
          else
            ((unsigned short*)outF)[(size_t)row * 1024 + (col - 512)] = f2bf(v);
        } else {
          size_t o = (size_t)row * N + col;
          if (EPI == 1) outB[o] = __float2bfloat16(v);
          else if (EPI == 2) outB[o] = __float2bfloat16(gelu_f(v));
          else outF[o] += v;
        }
      }
    }
  }
}

// ---------------- reference-token projection (tiny); refvT padded to stride 128 ----------------
__global__ __launch_bounds__(256) void ref_kernel(
    const float* __restrict__ x_ref, const float* __restrict__ w, const float* __restrict__ bias,
    const float* __restrict__ diff_mu, const float* __restrict__ diff_ls,
    unsigned short* __restrict__ refq, unsigned short* __restrict__ refvT) {
  int blk = blockIdx.x;               // 0..199
  int b = blk / 100, r = blk % 100;
  __shared__ float xs[512];
  int tid = threadIdx.x;
  const float* xr = x_ref + (size_t)(b * 100 + r) * 512;
  xs[tid] = xr[tid];
  xs[tid + 256] = xr[tid + 256];
  __syncthreads();
#pragma unroll
  for (int cc = 0; cc < 4; cc++) {
    int c = cc * 256 + tid;
    const float* wr = w + (size_t)c * 512;
    float s = bias[c];
    for (int k = 0; k < 512; k++) s += xs[k] * wr[k];
    if (c < 512) {
      float v = diff_mu[c] + expf(diff_ls[c]) * s;
      int hh = c >> 5, d = c & 31;
      refq[((size_t)(b * 16 + hh) * 100 + r) * 32 + d] = f2bf(v);
    } else {
      int c2 = c - 512, hh = c2 >> 5, d = c2 & 31;
      refvT[(((size_t)b * 16 + hh) * 32 + d) * 128 + r] = f2bf(s);
    }
  }
  // zero-fill pad cols 100..127 (28 pad cols; blocks r<28 each own one column)
  if (r < 28) {
#pragma unroll
    for (int j = 0; j < 2; j++) {
      int idx = j * 256 + tid;          // 0..511 = (hh, d)
      int hh = idx >> 5, d = idx & 31;
      refvT[(((size_t)b * 16 + hh) * 32 + d) * 128 + 100 + r] = 0;
    }
  }
}

// ---------------- ra = q @ ref_q^T ; MFMA ; block per (b_, head) ----------------
__global__ __launch_bounds__(256) void ra_kernel(
    const __hip_bfloat16* __restrict__ q, const unsigned short* __restrict__ refq,
    __hip_bfloat16* __restrict__ ra) {
  __shared__ __align__(16) unsigned short q_s[64 * 40];
  __shared__ __align__(16) unsigned short rq_s[112 * 40];
  int blk = blockIdx.x;               // 8192
  int b_ = blk >> 4, h = blk & 15;
  int rb = b_ >> 8, win = b_ & 255;
  int tid = threadIdx.x;
  int wave = tid >> 6, lane = tid & 63;
  int lrow = lane & 15, kq = lane >> 4;
  u32x4 z4 = {};
  const unsigned short* qb = (const unsigned short*)q + (size_t)b_ * 49 * 512 + h * 32;
  for (int i = tid; i < 196; i += 256) {
    int n = i >> 2, c = i & 3;
    *reinterpret_cast<u32x4*>(&q_s[n * 40 + c * 8]) =
        *reinterpret_cast<const u32x4*>(&qb[n * 512 + c * 8]);
  }
  for (int i = tid; i < 60; i += 256) {
    int n = 49 + (i >> 2), c = i & 3;
    *reinterpret_cast<u32x4*>(&q_s[n * 40 + c * 8]) = z4;
  }
  const unsigned short* rqg = refq + (size_t)(rb * 16 + h) * 3200;
  for (int i = tid; i < 400; i += 256) {
    int r = i >> 2, c = i & 3;
    *reinterpret_cast<u32x4*>(&rq_s[r * 40 + c * 8]) =
        *reinterpret_cast<const u32x4*>(&rqg[r * 32 + c * 8]);
  }
  for (int i = tid; i < 48; i += 256) {
    int r = 100 + (i >> 2), c = i & 3;
    *reinterpret_cast<u32x4*>(&rq_s[r * 40 + c * 8]) = z4;
  }
  __syncthreads();
  short8 a = *reinterpret_cast<const short8*>(&q_s[(wave * 16 + lrow) * 40 + kq * 8]);
  unsigned short* ra_base = (unsigned short*)ra + ((size_t)(rb * 16 + h) * 12544 + win * 49) * 100;
  f32x4 zero = {};
#pragma unroll
  for (int nt = 0; nt < 7; nt++) {
    short8 b = *reinterpret_cast<const short8*>(&rq_s[(nt * 16 + lrow) * 40 + kq * 8]);
    f32x4 c = __builtin_amdgcn_mfma_f32_16x16x32_bf16(a, b, zero, 0, 0, 0);
    int col = nt * 16 + lrow;
#pragma unroll
    for (int r = 0; r < 4; r++) {
      int n = wave * 16 + kq * 4 + r;
      if (n < 49 && col < 100) ra_base[n * 100 + col] = f2bf(c[r]);
    }
  }
}

// ---------------- implicit-GEMM MFMA conv v6: LDS-staged coalesced u stores ----------------
DEV int swzi(int pl, int ci) {
  int byte = (pl << 5) + (ci << 1);
  byte ^= ((pl >> 2) & 3) << 4;
  return byte >> 1;                   // ushort index
}
__global__ __launch_bounds__(256, 6) void conv_kernel(
    const __hip_bfloat16* __restrict__ ra_, const unsigned short* __restrict__ cwT,
    const float* __restrict__ cb,
    __hip_bfloat16* __restrict__ u_, float* __restrict__ psum, float* __restrict__ psumsq) {
  __shared__ __align__(16) unsigned short in_s[6 * 103 * 16];    // 19,776 B swizzled
  __shared__ __align__(16) unsigned short st_s[4 * 16 * 36];     //  4,608 B (stride 36 spreads banks)
  __shared__ float sred_s[4][16], sred_s2[4][16];
  const unsigned short* ra = (const unsigned short*)ra_;
  unsigned short* u = (unsigned short*)u_;
  int yt = blockIdx.x, bb = blockIdx.y;
  int y0 = yt * 4;
  int tid = threadIdx.x;
  int wave = tid >> 6, lane = tid & 63;
  int lrow = lane & 15, kq = lane >> 4;
  for (int i = tid; i < 288; i += 256) {
    int ci = i & 15, rem = i >> 4;
    int yl = rem / 3, xs = rem % 3;
    int xl = (xs == 0) ? 0 : (100 + xs);
    in_s[swzi(yl * 103 + xl, ci)] = 0;
  }
  if (tid < 192) {
    int unit = tid >> 1, par = tid & 1;
    int ci = unit / 6, yl = unit % 6;
    int gy = y0 - 1 + yl;
    bool rv = (gy >= 0 && gy < 12544);
    const unsigned short* rp = ra + (((size_t)bb * 16 + ci) * 12544 + (rv ? gy : 0)) * 100;
    int plb = yl * 103 + 1;
#pragma unroll 4
    for (int c = par; c < 25; c += 2) {
      u32x2 d = {0u, 0u};
      if (rv) d = *reinterpret_cast<const u32x2*>(&rp[c * 4]);
      int pl = plb + c * 4;
      in_s[swzi(pl + 0, ci)] = (unsigned short)(d[0] & 0xffff);
      in_s[swzi(pl + 1, ci)] = (unsigned short)(d[0] >> 16);
      in_s[swzi(pl + 2, ci)] = (unsigned short)(d[1] & 0xffff);
      in_s[swzi(pl + 3, ci)] = (unsigned short)(d[1] >> 16);
    }
  }
  __syncthreads();

  short8 afr[5];
#pragma unroll
  for (int c = 0; c < 5; c++)
    afr[c] = *reinterpret_cast<const short8*>(&cwT[lrow * 160 + c * 32 + kq * 8]);
  int kqh = kq >> 1, ci0 = (kq & 1) * 8;
  int kyA[5], kxA[5];
#pragma unroll
  for (int c = 0; c < 5; c++) {
    int p = c * 2 + kqh; if (p > 8) p = 0;
    kyA[c] = p / 3; kxA[c] = p % 3;
  }
  float bias_r[4];
#pragma unroll
  for (int r = 0; r < 4; r++) bias_r[r] = cb[kq * 4 + r];
  float s_r[4] = {0.f, 0.f, 0.f, 0.f}, s2_r[4] = {0.f, 0.f, 0.f, 0.f};

  int yl = wave;
  int gy = y0 + yl;
  unsigned short* stw = &st_s[wave * 16 * 36];
  int seg = lane >> 2, part = lane & 3;
  const size_t ubase = ((size_t)bb * 16 * 12544 + gy) * 100;   // + ch*12544*100 + px
#pragma unroll
  for (int xp = 0; xp < 4; xp++) {
#pragma unroll
    for (int xh = 0; xh < 2; xh++) {
      int xg = xp * 2 + xh;
      if (xg >= 7) break;
      int px = xg * 16 + lrow;
      int pxc = px < 100 ? px : 99;
      f32x4 acc = {};
#pragma unroll
      for (int c = 0; c < 5; c++) {
        short8 bfrag = *reinterpret_cast<const short8*>(
            &in_s[swzi((yl + kyA[c]) * 103 + pxc + kxA[c], ci0)]);
        acc = __builtin_amdgcn_mfma_f32_16x16x32_bf16(afr[c], bfrag, acc, 0, 0, 0);
      }
      bool valid = px < 100;
#pragma unroll
      for (int r = 0; r < 4; r++) {
        float v = acc[r] + bias_r[r];
        if (valid) {
          stw[(kq * 4 + r) * 36 + xh * 16 + lrow] = f2bf(v);
          s_r[r] += v; s2_r[r] += v * v;
        }
      }
    }
    // wave-synchronous coalesced store of the staged 16ch x 32px tile
    unsigned short* ug = u + ubase + (size_t)seg * 1254400;    // 12544*100
    if (xp < 3) {
      u32x2 d0 = *reinterpret_cast<const u32x2*>(&stw[seg * 36 + part * 4]);
      u32x2 d1 = *reinterpret_cast<const u32x2*>(&stw[seg * 36 + 16 + part * 4]);
      *reinterpret_cast<u32x2*>(&ug[xp * 32 + part * 4]) = d0;        // bytes 0..31 of chunk
      *reinterpret_cast<u32x2*>(&ug[xp * 32 + 16 + part * 4]) = d1;   // bytes 32..63
    } else if (lane < 16) {
      u32x2 d = *reinterpret_cast<const u32x2*>(&st_s[wave * 16 * 36 + lane * 36]);
      *reinterpret_cast<u32x2*>(&u[ubase + (size_t)lane * 1254400 + 96]) = d;
    }
  }
#pragma unroll
  for (int o = 1; o < 16; o <<= 1)
#pragma unroll
    for (int r = 0; r < 4; r++) { s_r[r] += __shfl_xor(s_r[r], o); s2_r[r] += __shfl_xor(s2_r[r], o); }
  if (lrow == 0)
#pragma unroll
    for (int r = 0; r < 4; r++) { sred_s[wave][kq * 4 + r] = s_r[r]; sred_s2[wave][kq * 4 + r] = s2_r[r]; }
  __syncthreads();
  if (tid < 16) {
    float s  = sred_s[0][tid] + sred_s[1][tid] + sred_s[2][tid] + sred_s[3][tid];
    float s2 = sred_s2[0][tid] + sred_s2[1][tid] + sred_s2[2][tid] + sred_s2[3][tid];
    size_t pi = ((size_t)bb * 3136 + yt) * 16 + tid;
    psum[pi] = s; psumsq[pi] = s2;
  }
}

__global__ __launch_bounds__(256) void conv_stats_kernel(
    const float* __restrict__ psum, const float* __restrict__ psumsq, float* __restrict__ stats) {
  int g = blockIdx.x;                 // 32 = (b, co)
  int bb = g >> 4, co = g & 15;
  int tid = threadIdx.x;
  float s = 0.f, s2 = 0.f;
  for (int t = tid; t < 3136; t += 256) {
    size_t pi = ((size_t)bb * 3136 + t) * 16 + co;
    s += psum[pi];
    s2 += psumsq[pi];
  }
  block_reduce2(s, s2);
  if (tid == 0) {
    const float inv = 1.f / 1254400.f;
    float mu = s * inv;
    float var = s2 * inv - mu * mu;
    stats[g * 2] = mu;
    stats[g * 2 + 1] = rsqrtf(var + 1e-5f);
  }
}

__global__ __launch_bounds__(256) void conv_apply_kernel(
    __hip_bfloat16* __restrict__ ra, const __hip_bfloat16* __restrict__ u,
    const float* __restrict__ stats) {
  const int total8 = 5017600;         // 40,140,800 / 8
  int stride = gridDim.x * 256;
  for (int i = blockIdx.x * 256 + threadIdx.x; i < total8; i += stride) {
    int g = i / 156800;               // 1,254,400 / 8 per (b,ch) group
    float mu = stats[g * 2], rstd = stats[g * 2 + 1];
    ushort8 uu = reinterpret_cast<const ushort8*>(u)[i];
    ushort8 rr = reinterpret_cast<const ushort8*>(ra)[i];
    ushort8 oo;
#pragma unroll
    for (int j = 0; j < 8; j++) {
      float rv = bf2f(rr[j]) + gelu_f((bf2f(uu[j]) - mu) * rstd);
      oo[j] = f2bf(rv);
    }
    reinterpret_cast<ushort8*>(ra)[i] = oo;
  }
}

// ---------------- fused MFMA attention (FUSE=1: P1 = ra + gelu(norm(u)) on the fly) ----------------
// LDS 18,944 B -> 8 blocks/CU (32-wave HW cap). rvT and K read as MFMA fragments DIRECTLY
// from global (L2-hot; refvT stride-128 pad / kv row stride 1024).
template <int FUSE>
__global__ __launch_bounds__(256, 8) void attn_kernel(
    const __hip_bfloat16* __restrict__ ra_, const __hip_bfloat16* __restrict__ u_,
    const float* __restrict__ stats, const unsigned short* __restrict__ refvT,
    const __hip_bfloat16* __restrict__ kv_, const unsigned short* __restrict__ rpbT,
    const unsigned short* __restrict__ maskB, __hip_bfloat16* __restrict__ att_) {
  __shared__ __align__(16) char smem[18944];
  unsigned short* P1 = (unsigned short*)smem;              // A: stride 136, rows 0..48 staged
  unsigned short* P2 = (unsigned short*)smem;              // B: stride 72, rows 0..63
  unsigned short* vT = (unsigned short*)(smem + 9216);     // B: stride 72, 32 rows
  unsigned short* qn = (unsigned short*)(smem + 13824);    // stride 40, 64 rows; cols 32..33 lsum

#define LSUM(n) (*reinterpret_cast<float*>(&qn[(n) * 40 + 32]))

  int blk = blockIdx.x;               // 8192
  int b_ = blk >> 4, h = blk & 15;
  int rb = b_ >> 8, win = b_ & 255;
  int tid = threadIdx.x;
  int wave = tid >> 6, lane = tid & 63;
  int lrow = lane & 15, kq = lane >> 4;
  const unsigned short* ra = (const unsigned short*)ra_;
  const unsigned short* ug = (const unsigned short*)u_;
  const unsigned short* kv = (const unsigned short*)kv_;
  unsigned short* att = (unsigned short*)att_;
  u32x2 zz = {};

  if (tid < 64) LSUM(tid) = 1.0f;
  float mu = 0.f, rstd = 0.f;
  if (FUSE) { mu = stats[(rb * 16 + h) * 2]; rstd = stats[(rb * 16 + h) * 2 + 1]; }

  const size_t tile_off = ((size_t)(rb * 16 + h) * 12544 + win * 49) * 100;
  const unsigned short* rab = ra + tile_off;
  const unsigned short* uab = ug + tile_off;
  for (int i = tid; i < 1225; i += 256) {
    int n = i / 25, c = i % 25;
    u32x2 rv = *reinterpret_cast<const u32x2*>(&rab[n * 100 + c * 4]);
    if (FUSE) {
      u32x2 uv = *reinterpret_cast<const u32x2*>(&uab[n * 100 + c * 4]);
      unsigned short rr4[4] = {(unsigned short)(rv[0] & 0xffff), (unsigned short)(rv[0] >> 16),
                               (unsigned short)(rv[1] & 0xffff), (unsigned short)(rv[1] >> 16)};
      unsigned short uu4[4] = {(unsigned short)(uv[0] & 0xffff), (unsigned short)(uv[0] >> 16),
                               (unsigned short)(uv[1] & 0xffff), (unsigned short)(uv[1] >> 16)};
      unsigned short o4[4];
#pragma unroll
      for (int j = 0; j < 4; j++)
        o4[j] = f2bf(bf2f(rr4[j]) + gelu_f((bf2f(uu4[j]) - mu) * rstd));
      u32x2 w;
      w[0] = (unsigned int)o4[0] | ((unsigned int)o4[1] << 16);
      w[1] = (unsigned int)o4[2] | ((unsigned int)o4[3] << 16);
      *reinterpret_cast<u32x2*>(&P1[n * 136 + c * 4]) = w;
    } else {
      *reinterpret_cast<u32x2*>(&P1[n * 136 + c * 4]) = rv;
    }
  }
  for (int i = tid; i < 343; i += 256) {
    int n = i / 7, c = i % 7;
    *reinterpret_cast<u32x2*>(&P1[n * 136 + 100 + c * 4]) = zz;
  }
  __syncthreads();

  // ---- register softmax over 100 ref slots; store raw e, defer 1/l to qn epilogue ----
  if (tid < 196) {
    int n = tid >> 2, q = tid & 3;
    unsigned short* row = P1 + n * 136 + q * 25;
    float e[25];
#pragma unroll
    for (int r = 0; r < 25; r++) e[r] = bf2f(row[r]);
    float mx = -1e30f;
#pragma unroll
    for (int r = 0; r < 25; r++) mx = fmaxf(mx, e[r]);
    mx = fmaxf(mx, __shfl_xor(mx, 1));
    mx = fmaxf(mx, __shfl_xor(mx, 2));
    float sm = 0.f;
#pragma unroll
    for (int r = 0; r < 25; r++) { e[r] = __expf(e[r] - mx); sm += e[r]; }
    sm += __shfl_xor(sm, 1);
    sm += __shfl_xor(sm, 2);
#pragma unroll
    for (int r = 0; r < 25; r++) row[r] = f2bf(e[r]);
    if (q == 0) LSUM(n) = sm;
  }
  __syncthreads();

  // ---- qnew = P1 @ rvT^T  (M=64, N=32, K=128); rvT fragments direct from global ----
  const unsigned short* rvtg = refvT + (size_t)(rb * 16 + h) * 4096;   // 32 x 128, zero-padded
  f32x4 acc1[2] = {};
#pragma unroll
  for (int ks = 0; ks < 4; ks++) {
    short8 a = *reinterpret_cast<const short8*>(&P1[(wave * 16 + lrow) * 136 + ks * 32 + kq * 8]);
#pragma unroll
    for (int dt = 0; dt < 2; dt++) {
      short8 b = *reinterpret_cast<const short8*>(&rvtg[(dt * 16 + lrow) * 128 + ks * 32 + kq * 8]);
      acc1[dt] = __builtin_amdgcn_mfma_f32_16x16x32_bf16(a, b, acc1[dt], 0, 0, 0);
    }
  }
  float invl[4];
#pragma unroll
  for (int r = 0; r < 4; r++)
    invl[r] = 0.17677669529663688f / LSUM(wave * 16 + kq * 4 + r);
#pragma unroll
  for (int dt = 0; dt < 2; dt++)
#pragma unroll
    for (int r = 0; r < 4; r++) {
      int n = wave * 16 + kq * 4 + r;
      qn[n * 40 + dt * 16 + lrow] = f2bf(acc1[dt][r] * invl[r]);
    }
  __syncthreads();

  // ---- phase B: stage v^T (register transpose) into dead P1 space ----
  const unsigned short* kvb = kv + (size_t)b_ * 49 * 1024;
  for (int i = tid; i < 196; i += 256) {
    int m = i >> 2, dg = (i & 3) * 8;
    ushort8 vv = *reinterpret_cast<const ushort8*>(&kvb[m * 1024 + 512 + h * 32 + dg]);
#pragma unroll
    for (int j = 0; j < 8; j++) vT[(dg + j) * 72 + m] = vv[j];
  }
  for (int i = tid; i < 480; i += 256) vT[(i / 15) * 72 + 49 + i % 15] = 0;
  __syncthreads();

  // ---- logits = qn @ K^T (N=64, K=32); K fragments direct from global; +rpb+mask; softmax ----
  const unsigned short* bt = maskB + (size_t)win * 2744;
  const unsigned short* rt = rpbT + (size_t)h * 2744;
  short8 aq = *reinterpret_cast<const short8*>(&qn[(wave * 16 + lrow) * 40 + kq * 8]);
  f32x4 zero = {};
  float val[4][4];
#pragma unroll
  for (int mt = 0; mt < 4; mt++) {
    int mrow = mt * 16 + lrow;
    int mc = mrow < 49 ? mrow : 48;           // clamp: garbage masked below, stays in-buffer
    short8 bk = *reinterpret_cast<const short8*>(&kvb[mc * 1024 + h * 32 + kq * 8]);
    f32x4 lg = __builtin_amdgcn_mfma_f32_16x16x32_bf16(aq, bk, zero, 0, 0, 0);
    int m = mrow;
#pragma unroll
    for (int r = 0; r < 4; r++) {
      int n = wave * 16 + kq * 4 + r;
      float v;
      if (m < 49 && n < 49)
        v = lg[r] + bf2f(rt[n * 56 + m]) + bf2f(bt[n * 56 + m]);
      else v = -1e30f;
      val[mt][r] = v;
    }
  }
#pragma unroll
  for (int r = 0; r < 4; r++) {
    float mx = -1e30f;
#pragma unroll
    for (int mt = 0; mt < 4; mt++) mx = fmaxf(mx, val[mt][r]);
    mx = fmaxf(mx, __shfl_xor(mx, 1)); mx = fmaxf(mx, __shfl_xor(mx, 2));
    mx = fmaxf(mx, __shfl_xor(mx, 4)); mx = fmaxf(mx, __shfl_xor(mx, 8));
    float sm = 0.f, e[4];
#pragma unroll
    for (int mt = 0; mt < 4; mt++) { e[mt] = __expf(val[mt][r] - mx); sm += e[mt]; }
    sm += __shfl_xor(sm, 1); sm += __shfl_xor(sm, 2);
    sm += __shfl_xor(sm, 4); sm += __shfl_xor(sm, 8);
    float inv = 1.f / sm;
    int n = wave * 16 + kq * 4 + r;
#pragma unroll
    for (int mt = 0; mt < 4; mt++) P2[n * 72 + mt * 16 + lrow] = f2bf(e[mt] * inv);
  }
  __syncthreads();

  // ---- out = P2 @ vT^T (N=32, K=64) -> global bf16 ----
  f32x4 acc2[2] = {};
#pragma unroll
  for (int ks = 0; ks < 2; ks++) {
    short8 ap = *reinterpret_cast<const short8*>(&P2[(wave * 16 + lrow) * 72 + ks * 32 + kq * 8]);
#pragma unroll
    for (int dt = 0; dt < 2; dt++) {
      short8 bv = *reinterpret_cast<const short8*>(&vT[(dt * 16 + lrow) * 72 + ks * 32 + kq * 8]);
      acc2[dt] = __builtin_amdgcn_mfma_f32_16x16x32_bf16(ap, bv, acc2[dt], 0, 0, 0);
    }
  }
  unsigned short* ab = att + (size_t)b_ * 49 * 512 + h * 32;
#pragma unroll
  for (int dt = 0; dt < 2; dt++)
#pragma unroll
    for (int r = 0; r < 4; r++) {
      int n = wave * 16 + kq * 4 + r;
      if (n < 49) ab[n * 512 + dt * 16 + lrow] = f2bf(acc2[dt][r]);
    }
#undef LSUM
}

// ---------------- window-reverse gather + residual + LN2 (wave-per-row) ----------------
__global__ __launch_bounds__(256) void resid_ln2_kernel(
    const float* __restrict__ x, const __hip_bfloat16* __restrict__ proj_out,
    const float* __restrict__ w2, const float* __restrict__ b2,
    float* __restrict__ out, __hip_bfloat16* __restrict__ hout) {
  int tid = threadIdx.x;
  int wave = tid >> 6, lane = tid & 63;
  int blk = blockIdx.x * 4 + wave;    // b*12544 + l
  int bb = blk / 12544, l = blk % 12544;
  int hh = l / 112, ww = l % 112;
  int hs = (hh + 109) % 112, wsx = (ww + 109) % 112;   // (h-3) mod 112
  int t = (bb * 256 + (hs / 7) * 16 + (wsx / 7)) * 49 + (hs % 7) * 7 + (wsx % 7);
  const float* xr = x + (size_t)blk * 512 + lane * 8;
  const unsigned short* pr = (const unsigned short*)proj_out + (size_t)t * 512 + lane * 8;
  f32x4 x0 = *reinterpret_cast<const f32x4*>(xr);
  f32x4 x1 = *reinterpret_cast<const f32x4*>(xr + 4);
  ushort8 p8 = *reinterpret_cast<const ushort8*>(pr);
  float v[8];
#pragma unroll
  for (int j = 0; j < 4; j++) {
    v[j]     = x0[j] + bf2f(p8[j]);
    v[4 + j] = x1[j] + bf2f(p8[4 + j]);
  }
  float s = 0.f, s2 = 0.f;
#pragma unroll
  for (int j = 0; j < 8; j++) { s += v[j]; s2 += v[j] * v[j]; }
  float* orow = out + (size_t)blk * 512 + lane * 8;
  f32x4 o0, o1;
#pragma unroll
  for (int j = 0; j < 4; j++) { o0[j] = v[j]; o1[j] = v[4 + j]; }
  *reinterpret_cast<f32x4*>(orow) = o0;
  *reinterpret_cast<f32x4*>(orow + 4) = o1;
#pragma unroll
  for (int o = 1; o < 64; o <<= 1) { s += __shfl_xor(s, o); s2 += __shfl_xor(s2, o); }
  float mu = s * (1.f / 512.f);
  float rstd = rsqrtf(s2 * (1.f / 512.f) - mu * mu + 1e-5f);
  f32x4 w0 = *reinterpret_cast<const f32x4*>(&w2[lane * 8]);
  f32x4 w1 = *reinterpret_cast<const f32x4*>(&w2[lane * 8 + 4]);
  f32x4 c0 = *reinterpret_cast<const f32x4*>(&b2[lane * 8]);
  f32x4 c1 = *reinterpret_cast<const f32x4*>(&b2[lane * 8 + 4]);
  ushort8 h8;
#pragma unroll
  for (int j = 0; j < 4; j++) {
    h8[j]     = f2bf((v[j] - mu) * rstd * w0[j] + c0[j]);
    h8[4 + j] = f2bf((v[4 + j] - mu) * rstd * w1[j] + c1[j]);
  }
  *reinterpret_cast<ushort8*>((unsigned short*)hout + (size_t)blk * 512 + lane * 8) = h8;
}

// =======================================================================
extern "C" void kernel_launch(void* const* d_in, const int* in_sizes, int n_in,
                              void* d_out, int out_size, void* d_ws, size_t ws_size,
                              hipStream_t stream) {
  const float* x       = (const float*)d_in[0];
  const float* x_ref   = (const float*)d_in[1];
  const float* mask    = (const float*)d_in[2];
  const float* n1w     = (const float*)d_in[3];
  const float* n1b     = (const float*)d_in[4];
  const float* qkv_w   = (const float*)d_in[5];
  const float* qkv_b   = (const float*)d_in[6];
  const float* diff_mu = (const float*)d_in[7];
  const float* diff_ls = (const float*)d_in[8];
  const float* rpb     = (const float*)d_in[9];
  const float* ref_w   = (const float*)d_in[10];
  const float* ref_b   = (const float*)d_in[11];
  const float* conv_w  = (const float*)d_in[12];
  const float* conv_b  = (const float*)d_in[13];
  const float* proj_w  = (const float*)d_in[14];
  const float* proj_b  = (const float*)d_in[15];
  const float* n2w     = (const float*)d_in[16];
  const float* n2b     = (const float*)d_in[17];
  const float* fc1_w   = (const float*)d_in[18];
  const float* fc1_b   = (const float*)d_in[19];
  const float* fc2_w   = (const float*)d_in[20];
  const float* fc2_b   = (const float*)d_in[21];
  float* out = (float*)d_out;

  char* ws = (char*)d_ws;
  size_t off = 0;
  auto alloc = [&](size_t bytes) -> char* {
    char* p = ws + off;
    off += (bytes + 255) & ~(size_t)255;
    return p;
  };
  // ---- persistent small buffers ----
  __hip_bfloat16* wq_bf = (__hip_bfloat16*)alloc(1536ULL * 512 * 2);   // q rows 0..511, kv rows 512..1535
  __hip_bfloat16* wp_bf = (__hip_bfloat16*)alloc(512ULL * 512 * 2);
  __hip_bfloat16* w1_bf = (__hip_bfloat16*)alloc(2048ULL * 512 * 2);
  __hip_bfloat16* w2_bf = (__hip_bfloat16*)alloc(512ULL * 2048 * 2);
  unsigned short* refq  = (unsigned short*)alloc(2ULL * 16 * 100 * 32 * 2);
  unsigned short* refvT = (unsigned short*)alloc(2ULL * 16 * 32 * 128 * 2);  // stride-128 padded
  unsigned short* maskB = (unsigned short*)alloc(256ULL * 49 * 56 * 2);
  unsigned short* rpbT  = (unsigned short*)alloc(16ULL * 49 * 56 * 2);
  unsigned short* cwT   = (unsigned short*)alloc(2560ULL * 2);            // conv weight fragments
  float* psum  = (float*)alloc(2ULL * 3136 * 16 * 4);
  float* psumq = (float*)alloc(2ULL * 3136 * 16 * 4);
  float* stats = (float*)alloc(64 * 4);
  // ---- aliased regions ----
  char* regX  = alloc(25088ULL * 512 * 2);      // xw_bf -> att_bf            (25.7 MB)
  char* regQ  = alloc(25088ULL * 512 * 2);      // q_bf  -> h_bf              (25.7 MB)
  char* regRA = alloc(2ULL * 16 * 12544 * 100 * 2);  // ra    -> hg (per-chunk) (80.3 MB)
  char* regU  = alloc(2ULL * 16 * 12544 * 100 * 2);  // u -> (kv_bf) + proj_bf  (80.3 MB)

  __hip_bfloat16* xw_bf   = (__hip_bfloat16*)regX;
  __hip_bfloat16* att_bf  = (__hip_bfloat16*)regX;                      // after attn
  __hip_bfloat16* q_bf    = (__hip_bfloat16*)regQ;
  __hip_bfloat16* h_bf    = (__hip_bfloat16*)regQ;                      // after ra_kernel
  __hip_bfloat16* ra      = (__hip_bfloat16*)regRA;
  __hip_bfloat16* hg      = (__hip_bfloat16*)regRA;                     // after attn (51.4MB/chunk)
  __hip_bfloat16* u       = (__hip_bfloat16*)regU;
  __hip_bfloat16* proj_bf = (__hip_bfloat16*)(regU + 51380224);         // after attn (25.7MB)

  // fused path needs u live through attn -> kv in a dedicated region if ws allows
  const size_t kv_bytes = 25088ULL * 1024 * 2;   // 51.4 MB
  bool fused = (ws_size >= off + kv_bytes);
  __hip_bfloat16* kv_bf = fused ? (__hip_bfloat16*)alloc(kv_bytes)
                                : (__hip_bfloat16*)regU;   // classic: aliases dead u

  // 1. weights -> bf16 ; bias tables
  f2b_kernel<<<3072, 256, 0, stream>>>(qkv_w, wq_bf, 786432);
  f2b_kernel<<<1024, 256, 0, stream>>>(proj_w, wp_bf, 262144);
  f2b_kernel<<<4096, 256, 0, stream>>>(fc1_w, w1_bf, 1048576);
  f2b_kernel<<<4096, 256, 0, stream>>>(fc2_w, w2_bf, 1048576);
  maskb_kernel<<<2744, 256, 0, stream>>>(mask, maskB);
  rpbt_kernel<<<172, 256, 0, stream>>>(rpb, rpbT);
  cwt_kernel<<<10, 256, 0, stream>>>(conv_w, cwT);
  // 2. LN1 + shift + window partition (wave-per-row)
  ln1_window_kernel<<<6272, 256, 0, stream>>>(x, n1w, n1b, xw_bf);
  // 3. q/kv projection
  if (fused) {
    // merged qkv GEMM: one A staging pass, outputs routed to q_bf / kv_bf (layouts unchanged)
    gemm_bt<4><<<2352, 256, 0, stream>>>(xw_bf, wq_bf, qkv_b, (float*)kv_bf, q_bf,
                                         25088, 1536, 512);
  } else {
    gemm_bt<1><<<784, 256, 0, stream>>>(xw_bf, wq_bf, qkv_b, nullptr, q_bf,
                                        25088, 512, 512);
  }
  // 4. reference tokens
  ref_kernel<<<200, 256, 0, stream>>>(x_ref, ref_w, ref_b, diff_mu, diff_ls, refq, refvT);
  // 5. ra = q @ ref_q^T (MFMA)
  ra_kernel<<<8192, 256, 0, stream>>>(q_bf, refq, ra);
  // 6. conv diffusion x3 (apply of round 3 folded into attn when fused)
  for (int rd = 0; rd < 3; rd++) {
    conv_kernel<<<dim3(3136, 2), 256, 0, stream>>>(ra, cwT, conv_b, u, psum, psumq);
    conv_stats_kernel<<<32, 256, 0, stream>>>(psum, psumq, stats);
    if (rd < 2 || !fused)
      conv_apply_kernel<<<4096, 256, 0, stream>>>(ra, u, stats);
  }
  // 7. classic path: kv GEMM into dead-u alias (fused path did it in step 3)
  if (!fused)
    gemm_bt<1><<<1568, 256, 0, stream>>>(xw_bf, wq_bf + 512 * 512, qkv_b + 512,
                                         nullptr, kv_bf, 25088, 1024, 512);
  // 8. fused MFMA attention (xw dead -> att_bf)
  if (fused)
    attn_kernel<1><<<8192, 256, 0, stream>>>(ra, u, stats, refvT, kv_bf, rpbT, maskB, att_bf);
  else
    attn_kernel<0><<<8192, 256, 0, stream>>>(ra, u, stats, refvT, kv_bf, rpbT, maskB, att_bf);
  // 9. proj GEMM (bias -> bf16, into regU tail; u dead after attn)
  gemm_bt<1><<<784, 256, 0, stream>>>(att_bf, wp_bf, proj_b, nullptr, proj_bf,
                                      25088, 512, 512);
  // 10. window reverse + residual + LN2 (wave-per-row; h_bf into dead q region)
  resid_ln2_kernel<<<6272, 256, 0, stream>>>(x, proj_bf, n2w, n2b, out, h_bf);
  // 11. MLP in two M-chunks; hg reuses dead ra region
  for (int ch = 0; ch < 2; ch++) {
    const __hip_bfloat16* hA = h_bf + (size_t)ch * 12544 * 512;
    gemm_bt<2><<<1568, 256, 0, stream>>>(hA, w1_bf, fc1_b, nullptr, hg,
                                         12544, 2048, 512);
    gemm_bt<3><<<392, 256, 0, stream>>>(hg, w2_bf, fc2_b,
                                        out + (size_t)ch * 12544 * 512, nullptr,
                                        12544, 512, 2048);
  }
}

// Round 9
// 1086.789 us; speedup vs baseline: 1.0394x; 1.0394x over previous
//
#include <hip/hip_runtime.h>
#include <hip/hip_bf16.h>

typedef __attribute__((ext_vector_type(8))) short short8;        // 8 bf16 = 4 VGPRs
typedef __attribute__((ext_vector_type(8))) unsigned short ushort8;
typedef __attribute__((ext_vector_type(4))) float f32x4;
typedef __attribute__((ext_vector_type(4))) unsigned int u32x4;
typedef __attribute__((ext_vector_type(2))) unsigned int u32x2;

#define DEV __device__ __forceinline__

DEV float gelu_f(float x) { return 0.5f * x * (1.f + erff(x * 0.70710678118654752440f)); }

DEV float bf2f(unsigned short s) {
  unsigned int t = ((unsigned int)s) << 16;
  float f; __builtin_memcpy(&f, &t, 4); return f;
}
DEV unsigned short f2bf(float f) {
  __hip_bfloat16 b = __float2bfloat16(f);
  unsigned short s; __builtin_memcpy(&s, &b, 2); return s;
}

// async global->LDS 16B/lane (dest = wave-uniform base + lane*16)
DEV void async_copy16(void* lds, const void* g) {
  __builtin_amdgcn_global_load_lds(
      (const __attribute__((address_space(1))) unsigned int*)g,
      (__attribute__((address_space(3))) unsigned int*)lds, 16, 0, 0);
}

// block-wide (256 thr) sum of two values; every thread gets the totals
DEV void block_reduce2(float& s, float& s2) {
  __shared__ float red[8];
  int tid = threadIdx.x;
#pragma unroll
  for (int o = 32; o > 0; o >>= 1) { s += __shfl_down(s, o); s2 += __shfl_down(s2, o); }
  if ((tid & 63) == 0) { red[tid >> 6] = s; red[4 + (tid >> 6)] = s2; }
  __syncthreads();
  s  = red[0] + red[1] + red[2] + red[3];
  s2 = red[4] + red[5] + red[6] + red[7];
}

// ---------------- all four weight tensors fp32 -> bf16, one dispatch, vectorized ----------------
__global__ __launch_bounds__(256) void f2b_all_kernel(
    const float* __restrict__ qkv_w, const float* __restrict__ proj_w,
    const float* __restrict__ fc1_w, const float* __restrict__ fc2_w,
    __hip_bfloat16* __restrict__ wq, __hip_bfloat16* __restrict__ wp,
    __hip_bfloat16* __restrict__ w1, __hip_bfloat16* __restrict__ w2) {
  int i = blockIdx.x * 256 + threadIdx.x;          // unit = 8 elems; total 393216 units
  const float* src; unsigned short* dst; int o;
  if (i < 98304)       { src = qkv_w;  dst = (unsigned short*)wq; o = i; }
  else if (i < 131072) { src = proj_w; dst = (unsigned short*)wp; o = i - 98304; }
  else if (i < 262144) { src = fc1_w;  dst = (unsigned short*)w1; o = i - 131072; }
  else                 { src = fc2_w;  dst = (unsigned short*)w2; o = i - 262144; }
  f32x4 a = *reinterpret_cast<const f32x4*>(&src[(size_t)o * 8]);
  f32x4 b = *reinterpret_cast<const f32x4*>(&src[(size_t)o * 8 + 4]);
  ushort8 v;
#pragma unroll
  for (int j = 0; j < 4; j++) { v[j] = f2bf(a[j]); v[4 + j] = f2bf(b[j]); }
  *reinterpret_cast<ushort8*>(&dst[(size_t)o * 8]) = v;
}

// ---------------- mask -> bf16 padded [win][49][56] ----------------
__global__ __launch_bounds__(256) void maskb_kernel(const float* __restrict__ mask,
                                                    unsigned short* __restrict__ maskB) {
  int i = blockIdx.x * 256 + threadIdx.x;          // 256*49*56 = 702464 exactly
  int m = i % 56, rest = i / 56;
  int n = rest % 49, win = rest / 49;
  unsigned short v = 0;
  if (m < 49) v = f2bf(mask[((size_t)win * 49 + n) * 49 + m]);
  maskB[i] = v;
}

// ---------------- rpb -> bf16 padded [h][49][56] ----------------
__global__ __launch_bounds__(256) void rpbt_kernel(const float* __restrict__ rpb,
                                                   unsigned short* __restrict__ rpbT) {
  int i = blockIdx.x * 256 + threadIdx.x;          // 16*49*56 = 43904
  if (i >= 43904) return;
  int m = i % 56, rest = i / 56;
  int n = rest % 49, h = rest / 49;
  unsigned short v = 0;
  if (m < 49) {
    int rp = (n / 7 - m / 7 + 6) * 13 + (n % 7 - m % 7 + 6);
    v = f2bf(rpb[rp * 16 + h]);
  }
  rpbT[i] = v;
}

// ---------------- conv weight fragment table [co=16][160] (shared by all conv blocks) ----------------
__global__ __launch_bounds__(256) void cwt_kernel(const float* __restrict__ cw,
                                                  unsigned short* __restrict__ cwT) {
  int i = blockIdx.x * 256 + threadIdx.x;          // 2560
  if (i >= 2560) return;
  int co = i / 160, k = i % 160;
  unsigned short v = 0;
  if (k < 144) {
    int ci = k & 15, p = k >> 4;
    v = f2bf(cw[(co * 16 + ci) * 9 + p]);
  }
  cwT[i] = v;
}

// ---------------- LN1 + cyclic shift + window partition -> bf16 (wave-per-row) ----------------
__global__ __launch_bounds__(256) void ln1_window_kernel(
    const float* __restrict__ x, const float* __restrict__ w, const float* __restrict__ b,
    __hip_bfloat16* __restrict__ xw) {
  int tid = threadIdx.x;
  int wave = tid >> 6, lane = tid & 63;
  int t = blockIdx.x * 4 + wave;      // 0..25087
  int b_ = t / 49, n = t % 49;
  int bb = b_ >> 8, win = b_ & 255;
  int wi = win >> 4, wj = win & 15;
  int ii = n / 7, jj = n % 7;
  int sh = (wi * 7 + ii + 3) % 112;
  int sw = (wj * 7 + jj + 3) % 112;
  const float* row = x + ((size_t)bb * 12544 + sh * 112 + sw) * 512;
  f32x4 v0 = *reinterpret_cast<const f32x4*>(&row[lane * 8]);
  f32x4 v1 = *reinterpret_cast<const f32x4*>(&row[lane * 8 + 4]);
  float s = 0.f, s2 = 0.f;
#pragma unroll
  for (int j = 0; j < 4; j++) {
    s += v0[j] + v1[j];
    s2 += v0[j] * v0[j] + v1[j] * v1[j];
  }
#pragma unroll
  for (int o = 1; o < 64; o <<= 1) { s += __shfl_xor(s, o); s2 += __shfl_xor(s2, o); }
  float mu = s * (1.f / 512.f);
  float rstd = rsqrtf(s2 * (1.f / 512.f) - mu * mu + 1e-5f);
  f32x4 w0 = *reinterpret_cast<const f32x4*>(&w[lane * 8]);
  f32x4 w1 = *reinterpret_cast<const f32x4*>(&w[lane * 8 + 4]);
  f32x4 c0 = *reinterpret_cast<const f32x4*>(&b[lane * 8]);
  f32x4 c1 = *reinterpret_cast<const f32x4*>(&b[lane * 8 + 4]);
  ushort8 o8;
#pragma unroll
  for (int j = 0; j < 4; j++) {
    o8[j]     = f2bf((v0[j] - mu) * rstd * w0[j] + c0[j]);
    o8[4 + j] = f2bf((v1[j] - mu) * rstd * w1[j] + c1[j]);
  }
  *reinterpret_cast<ushort8*>((unsigned short*)xw + (size_t)t * 512 + lane * 8) = o8;
}

// ---------------- bf16 MFMA GEMM v2: double-buffered LDS (stage t+1 before compute t) ----
// EPI: 1 = bias -> bf16 store ; 2 = bias+gelu -> bf16 ; 3 = bias -> f32 +=
//      4 = merged qkv: col<512 -> q_bf (stride 512), col>=512 -> kv_bf (stride 1024)
// 1-D grid + bijective XCD swizzle (n fastest within an XCD chunk).
template <int EPI>
__global__ __launch_bounds__(256) void gemm_bt(
    const __hip_bfloat16* __restrict__ A, const __hip_bfloat16* __restrict__ B,
    const float* __restrict__ bias, float* __restrict__ outF,
    __hip_bfloat16* __restrict__ outB, int M, int N, int K) {
  __shared__ __align__(16) __hip_bfloat16 As[2][128 * 64];   // unpadded (global_load_lds layout)
  __shared__ __align__(16) __hip_bfloat16 Bs[2][128 * 64];
  int nn = N >> 7;
  int nblk = gridDim.x;
  int bid = blockIdx.x;
  int xcd = bid & 7, slot = bid >> 3;
  int q8 = nblk >> 3, r8 = nblk & 7;
  int base = xcd < r8 ? xcd * (q8 + 1) : r8 * (q8 + 1) + (xcd - r8) * q8;
  int lin = base + slot;              // bijective; n fastest
  int m0 = (lin / nn) << 7, n0 = (lin % nn) << 7;
  int tid = threadIdx.x;
  int wave = tid >> 6, lane = tid & 63;
  int wm = (wave & 1) * 64, wn = (wave >> 1) * 64;
  int lrow = lane & 15, kq = lane >> 4;
  int srow = lane >> 3, scol = (lane & 7) * 8;     // staging: 8 rows x 64 cols per wave-inst
  int rb = wave * 32;
  const __hip_bfloat16* Abase = A + (size_t)m0 * K;
  const __hip_bfloat16* Bbase = B + (size_t)n0 * K;
  // prologue: stage tile 0 into buffer 0
#pragma unroll
  for (int i = 0; i < 4; i++) {
    int row = rb + i * 8 + srow;
    async_copy16(&As[0][(rb + i * 8) * 64], &Abase[(size_t)row * K + scol]);
    async_copy16(&Bs[0][(rb + i * 8) * 64], &Bbase[(size_t)row * K + scol]);
  }
  __syncthreads();
  f32x4 acc[4][4] = {};
  int nk = K >> 6;
  for (int t = 0; t < nk; t++) {
    int cur = t & 1;
    if (t + 1 < nk) {
      int k0 = (t + 1) << 6;
#pragma unroll
      for (int i = 0; i < 4; i++) {
        int row = rb + i * 8 + srow;
        async_copy16(&As[cur ^ 1][(rb + i * 8) * 64], &Abase[(size_t)row * K + k0 + scol]);
        async_copy16(&Bs[cur ^ 1][(rb + i * 8) * 64], &Bbase[(size_t)row * K + k0 + scol]);
      }
    }
#pragma unroll
    for (int ks = 0; ks < 2; ks++) {
      short8 af[4], bf[4];
#pragma unroll
      for (int u = 0; u < 4; u++) {
        af[u] = *reinterpret_cast<const short8*>(&As[cur][(wm + u * 16 + lrow) * 64 + ks * 32 + kq * 8]);
        bf[u] = *reinterpret_cast<const short8*>(&Bs[cur][(wn + u * 16 + lrow) * 64 + ks * 32 + kq * 8]);
      }
#pragma unroll
      for (int tm = 0; tm < 4; tm++)
#pragma unroll
        for (int tn = 0; tn < 4; tn++)
          acc[tm][tn] = __builtin_amdgcn_mfma_f32_16x16x32_bf16(af[tm], bf[tn], acc[tm][tn], 0, 0, 0);
    }
    __syncthreads();   // drains stage(t+1) loads (overlapped with the MFMAs above) +
                       // guards buf[cur] reuse at t+2
  }
  // D: row=(lane>>4)*4+r, col=lane&15 (verified gfx950 C/D layout)
#pragma unroll
  for (int tm = 0; tm < 4; tm++) {
#pragma unroll
    for (int tn = 0; tn < 4; tn++) {
      int col = n0 + wn + tn * 16 + lrow;
      float bv = bias[col];
#pragma unroll
      for (int r = 0; r < 4; r++) {
        int row = m0 + wm + tm * 16 + kq * 4 + r;
        float v = acc[tm][tn][r] + bv;
        if (EPI == 4) {
          if (col < 512)
            ((unsigned short*)outB)[(size_t)row * 512 + col] = f2bf(v);
          else
            ((unsigned short*)outF)[(size_t)row * 1024 + (col - 512)] = f2bf(v);
        } else {
          size_t o = (size_t)row * N + col;
          if (EPI == 1) outB[o] = __float2bfloat16(v);
          else if (EPI == 2) outB[o] = __float2bfloat16(gelu_f(v));
          else outF[o] += v;
        }
      }
    }
  }
}

// ---------------- reference-token projection (tiny); refvT padded to stride 128 ----------------
__global__ __launch_bounds__(256) void ref_kernel(
    const float* __restrict__ x_ref, const float* __restrict__ w, const float* __restrict__ bias,
    const float* __restrict__ diff_mu, const float* __restrict__ diff_ls,
    unsigned short* __restrict__ refq, unsigned short* __restrict__ refvT) {
  int blk = blockIdx.x;               // 0..199
  int b = blk / 100, r = blk % 100;
  __shared__ float xs[512];
  int tid = threadIdx.x;
  const float* xr = x_ref + (size_t)(b * 100 + r) * 512;
  xs[tid] = xr[tid];
  xs[tid + 256] = xr[tid + 256];
  __syncthreads();
#pragma unroll
  for (int cc = 0; cc < 4; cc++) {
    int c = cc * 256 + tid;
    const float* wr = w + (size_t)c * 512;
    float s = bias[c];
    for (int k = 0; k < 512; k++) s += xs[k] * wr[k];
    if (c < 512) {
      float v = diff_mu[c] + expf(diff_ls[c]) * s;
      int hh = c >> 5, d = c & 31;
      refq[((size_t)(b * 16 + hh) * 100 + r) * 32 + d] = f2bf(v);
    } else {
      int c2 = c - 512, hh = c2 >> 5, d = c2 & 31;
      refvT[(((size_t)b * 16 + hh) * 32 + d) * 128 + r] = f2bf(s);
    }
  }
  // zero-fill pad cols 100..127 (28 pad cols; blocks r<28 each own one column)
  if (r < 28) {
#pragma unroll
    for (int j = 0; j < 2; j++) {
      int idx = j * 256 + tid;          // 0..511 = (hh, d)
      int hh = idx >> 5, d = idx & 31;
      refvT[(((size_t)b * 16 + hh) * 32 + d) * 128 + 100 + r] = 0;
    }
  }
}

// ---------------- ra = q @ ref_q^T ; MFMA ; block per (b_, head) ----------------
// XCD-chunked blk: the 16 head-blocks of a window share the q tile -> same-XCD L2.
__global__ __launch_bounds__(256) void ra_kernel(
    const __hip_bfloat16* __restrict__ q, const unsigned short* __restrict__ refq,
    __hip_bfloat16* __restrict__ ra) {
  __shared__ __align__(16) unsigned short q_s[64 * 40];
  __shared__ __align__(16) unsigned short rq_s[112 * 40];
  int bid = blockIdx.x;               // 8192 (%8==0 -> bijective chunking)
  int blk = (bid & 7) * 1024 + (bid >> 3);
  int b_ = blk >> 4, h = blk & 15;
  int rb = b_ >> 8, win = b_ & 255;
  int tid = threadIdx.x;
  int wave = tid >> 6, lane = tid & 63;
  int lrow = lane & 15, kq = lane >> 4;
  u32x4 z4 = {};
  const unsigned short* qb = (const unsigned short*)q + (size_t)b_ * 49 * 512 + h * 32;
  for (int i = tid; i < 196; i += 256) {
    int n = i >> 2, c = i & 3;
    *reinterpret_cast<u32x4*>(&q_s[n * 40 + c * 8]) =
        *reinterpret_cast<const u32x4*>(&qb[n * 512 + c * 8]);
  }
  for (int i = tid; i < 60; i += 256) {
    int n = 49 + (i >> 2), c = i & 3;
    *reinterpret_cast<u32x4*>(&q_s[n * 40 + c * 8]) = z4;
  }
  const unsigned short* rqg = refq + (size_t)(rb * 16 + h) * 3200;
  for (int i = tid; i < 400; i += 256) {
    int r = i >> 2, c = i & 3;
    *reinterpret_cast<u32x4*>(&rq_s[r * 40 + c * 8]) =
        *reinterpret_cast<const u32x4*>(&rqg[r * 32 + c * 8]);
  }
  for (int i = tid; i < 48; i += 256) {
    int r = 100 + (i >> 2), c = i & 3;
    *reinterpret_cast<u32x4*>(&rq_s[r * 40 + c * 8]) = z4;
  }
  __syncthreads();
  short8 a = *reinterpret_cast<const short8*>(&q_s[(wave * 16 + lrow) * 40 + kq * 8]);
  unsigned short* ra_base = (unsigned short*)ra + ((size_t)(rb * 16 + h) * 12544 + win * 49) * 100;
  f32x4 zero = {};
#pragma unroll
  for (int nt = 0; nt < 7; nt++) {
    short8 b = *reinterpret_cast<const short8*>(&rq_s[(nt * 16 + lrow) * 40 + kq * 8]);
    f32x4 c = __builtin_amdgcn_mfma_f32_16x16x32_bf16(a, b, zero, 0, 0, 0);
    int col = nt * 16 + lrow;
#pragma unroll
    for (int r = 0; r < 4; r++) {
      int n = wave * 16 + kq * 4 + r;
      if (n < 49 && col < 100) ra_base[n * 100 + col] = f2bf(c[r]);
    }
  }
}

// ---------------- implicit-GEMM MFMA conv v6: LDS-staged coalesced u stores ----------------
// XCD-chunked yt: neighbor row-tiles (sharing halo rows + streaming adjacent ra/u) stay on
// one XCD's L2.
DEV int swzi(int pl, int ci) {
  int byte = (pl << 5) + (ci << 1);
  byte ^= ((pl >> 2) & 3) << 4;
  return byte >> 1;                   // ushort index
}
__global__ __launch_bounds__(256, 6) void conv_kernel(
    const __hip_bfloat16* __restrict__ ra_, const unsigned short* __restrict__ cwT,
    const float* __restrict__ cb,
    __hip_bfloat16* __restrict__ u_, float* __restrict__ psum, float* __restrict__ psumsq) {
  __shared__ __align__(16) unsigned short in_s[6 * 103 * 16];    // 19,776 B swizzled
  __shared__ __align__(16) unsigned short st_s[4 * 16 * 36];     //  4,608 B (stride 36 spreads banks)
  __shared__ float sred_s[4][16], sred_s2[4][16];
  const unsigned short* ra = (const unsigned short*)ra_;
  unsigned short* u = (unsigned short*)u_;
  int ytb = blockIdx.x;               // 3136 (%8==0)
  int yt = (ytb & 7) * 392 + (ytb >> 3);
  int bb = blockIdx.y;
  int y0 = yt * 4;
  int tid = threadIdx.x;
  int wave = tid >> 6, lane = tid & 63;
  int lrow = lane & 15, kq = lane >> 4;
  for (int i = tid; i < 288; i += 256) {
    int ci = i & 15, rem = i >> 4;
    int yl = rem / 3, xs = rem % 3;
    int xl = (xs == 0) ? 0 : (100 + xs);
    in_s[swzi(yl * 103 + xl, ci)] = 0;
  }
  if (tid < 192) {
    int unit = tid >> 1, par = tid & 1;
    int ci = unit / 6, yl = unit % 6;
    int gy = y0 - 1 + yl;
    bool rv = (gy >= 0 && gy < 12544);
    const unsigned short* rp = ra + (((size_t)bb * 16 + ci) * 12544 + (rv ? gy : 0)) * 100;
    int plb = yl * 103 + 1;
#pragma unroll 4
    for (int c = par; c < 25; c += 2) {
      u32x2 d = {0u, 0u};
      if (rv) d = *reinterpret_cast<const u32x2*>(&rp[c * 4]);
      int pl = plb + c * 4;
      in_s[swzi(pl + 0, ci)] = (unsigned short)(d[0] & 0xffff);
      in_s[swzi(pl + 1, ci)] = (unsigned short)(d[0] >> 16);
      in_s[swzi(pl + 2, ci)] = (unsigned short)(d[1] & 0xffff);
      in_s[swzi(pl + 3, ci)] = (unsigned short)(d[1] >> 16);
    }
  }
  __syncthreads();

  short8 afr[5];
#pragma unroll
  for (int c = 0; c < 5; c++)
    afr[c] = *reinterpret_cast<const short8*>(&cwT[lrow * 160 + c * 32 + kq * 8]);
  int kqh = kq >> 1, ci0 = (kq & 1) * 8;
  int kyA[5], kxA[5];
#pragma unroll
  for (int c = 0; c < 5; c++) {
    int p = c * 2 + kqh; if (p > 8) p = 0;
    kyA[c] = p / 3; kxA[c] = p % 3;
  }
  float bias_r[4];
#pragma unroll
  for (int r = 0; r < 4; r++) bias_r[r] = cb[kq * 4 + r];
  float s_r[4] = {0.f, 0.f, 0.f, 0.f}, s2_r[4] = {0.f, 0.f, 0.f, 0.f};

  int yl = wave;
  int gy = y0 + yl;
  unsigned short* stw = &st_s[wave * 16 * 36];
  int seg = lane >> 2, part = lane & 3;
  const size_t ubase = ((size_t)bb * 16 * 12544 + gy) * 100;   // + ch*12544*100 + px
#pragma unroll
  for (int xp = 0; xp < 4; xp++) {
#pragma unroll
    for (int xh = 0; xh < 2; xh++) {
      int xg = xp * 2 + xh;
      if (xg >= 7) break;
      int px = xg * 16 + lrow;
      int pxc = px < 100 ? px : 99;
      f32x4 acc = {};
#pragma unroll
      for (int c = 0; c < 5; c++) {
        short8 bfrag = *reinterpret_cast<const short8*>(
            &in_s[swzi((yl + kyA[c]) * 103 + pxc + kxA[c], ci0)]);
        acc = __builtin_amdgcn_mfma_f32_16x16x32_bf16(afr[c], bfrag, acc, 0, 0, 0);
      }
      bool valid = px < 100;
#pragma unroll
      for (int r = 0; r < 4; r++) {
        float v = acc[r] + bias_r[r];
        if (valid) {
          stw[(kq * 4 + r) * 36 + xh * 16 + lrow] = f2bf(v);
          s_r[r] += v; s2_r[r] += v * v;
        }
      }
    }
    // wave-synchronous coalesced store of the staged 16ch x 32px tile
    unsigned short* ug = u + ubase + (size_t)seg * 1254400;    // 12544*100
    if (xp < 3) {
      u32x2 d0 = *reinterpret_cast<const u32x2*>(&stw[seg * 36 + part * 4]);
      u32x2 d1 = *reinterpret_cast<const u32x2*>(&stw[seg * 36 + 16 + part * 4]);
      *reinterpret_cast<u32x2*>(&ug[xp * 32 + part * 4]) = d0;        // bytes 0..31 of chunk
      *reinterpret_cast<u32x2*>(&ug[xp * 32 + 16 + part * 4]) = d1;   // bytes 32..63
    } else if (lane < 16) {
      u32x2 d = *reinterpret_cast<const u32x2*>(&st_s[wave * 16 * 36 + lane * 36]);
      *reinterpret_cast<u32x2*>(&u[ubase + (size_t)lane * 1254400 + 96]) = d;
    }
  }
#pragma unroll
  for (int o = 1; o < 16; o <<= 1)
#pragma unroll
    for (int r = 0; r < 4; r++) { s_r[r] += __shfl_xor(s_r[r], o); s2_r[r] += __shfl_xor(s2_r[r], o); }
  if (lrow == 0)
#pragma unroll
    for (int r = 0; r < 4; r++) { sred_s[wave][kq * 4 + r] = s_r[r]; sred_s2[wave][kq * 4 + r] = s2_r[r]; }
  __syncthreads();
  if (tid < 16) {
    float s  = sred_s[0][tid] + sred_s[1][tid] + sred_s[2][tid] + sred_s[3][tid];
    float s2 = sred_s2[0][tid] + sred_s2[1][tid] + sred_s2[2][tid] + sred_s2[3][tid];
    size_t pi = ((size_t)bb * 3136 + yt) * 16 + tid;
    psum[pi] = s; psumsq[pi] = s2;
  }
}

__global__ __launch_bounds__(256) void conv_stats_kernel(
    const float* __restrict__ psum, const float* __restrict__ psumsq, float* __restrict__ stats) {
  int g = blockIdx.x;                 // 32 = (b, co)
  int bb = g >> 4, co = g & 15;
  int tid = threadIdx.x;
  float s = 0.f, s2 = 0.f;
  for (int t = tid; t < 3136; t += 256) {
    size_t pi = ((size_t)bb * 3136 + t) * 16 + co;
    s += psum[pi];
    s2 += psumsq[pi];
  }
  block_reduce2(s, s2);
  if (tid == 0) {
    const float inv = 1.f / 1254400.f;
    float mu = s * inv;
    float var = s2 * inv - mu * mu;
    stats[g * 2] = mu;
    stats[g * 2 + 1] = rsqrtf(var + 1e-5f);
  }
}

__global__ __launch_bounds__(256) void conv_apply_kernel(
    __hip_bfloat16* __restrict__ ra, const __hip_bfloat16* __restrict__ u,
    const float* __restrict__ stats) {
  const int total8 = 5017600;         // 40,140,800 / 8
  int stride = gridDim.x * 256;
  for (int i = blockIdx.x * 256 + threadIdx.x; i < total8; i += stride) {
    int g = i / 156800;               // 1,254,400 / 8 per (b,ch) group
    float mu = stats[g * 2], rstd = stats[g * 2 + 1];
    ushort8 uu = reinterpret_cast<const ushort8*>(u)[i];
    ushort8 rr = reinterpret_cast<const ushort8*>(ra)[i];
    ushort8 oo;
#pragma unroll
    for (int j = 0; j < 8; j++) {
      float rv = bf2f(rr[j]) + gelu_f((bf2f(uu[j]) - mu) * rstd);
      oo[j] = f2bf(rv);
    }
    reinterpret_cast<ushort8*>(ra)[i] = oo;
  }
}

// ---------------- fused MFMA attention (FUSE=1: P1 = ra + gelu(norm(u)) on the fly) ----------------
// LDS 18,944 B -> 8 blocks/CU (32-wave HW cap). rvT and K read as MFMA fragments DIRECTLY
// from global. XCD-chunked blk: the 16 head-blocks of a window share the kv tile -> same-XCD L2.
template <int FUSE>
__global__ __launch_bounds__(256, 8) void attn_kernel(
    const __hip_bfloat16* __restrict__ ra_, const __hip_bfloat16* __restrict__ u_,
    const float* __restrict__ stats, const unsigned short* __restrict__ refvT,
    const __hip_bfloat16* __restrict__ kv_, const unsigned short* __restrict__ rpbT,
    const unsigned short* __restrict__ maskB, __hip_bfloat16* __restrict__ att_) {
  __shared__ __align__(16) char smem[18944];
  unsigned short* P1 = (unsigned short*)smem;              // A: stride 136, rows 0..48 staged
  unsigned short* P2 = (unsigned short*)smem;              // B: stride 72, rows 0..63
  unsigned short* vT = (unsigned short*)(smem + 9216);     // B: stride 72, 32 rows
  unsigned short* qn = (unsigned short*)(smem + 13824);    // stride 40, 64 rows; cols 32..33 lsum

#define LSUM(n) (*reinterpret_cast<float*>(&qn[(n) * 40 + 32]))

  int bid = blockIdx.x;               // 8192 (%8==0 -> bijective chunking)
  int blk = (bid & 7) * 1024 + (bid >> 3);
  int b_ = blk >> 4, h = blk & 15;
  int rb = b_ >> 8, win = b_ & 255;
  int tid = threadIdx.x;
  int wave = tid >> 6, lane = tid & 63;
  int lrow = lane & 15, kq = lane >> 4;
  const unsigned short* ra = (const unsigned short*)ra_;
  const unsigned short* ug = (const unsigned short*)u_;
  const unsigned short* kv = (const unsigned short*)kv_;
  unsigned short* att = (unsigned short*)att_;
  u32x2 zz = {};

  if (tid < 64) LSUM(tid) = 1.0f;
  float mu = 0.f, rstd = 0.f;
  if (FUSE) { mu = stats[(rb * 16 + h) * 2]; rstd = stats[(rb * 16 + h) * 2 + 1]; }

  const size_t tile_off = ((size_t)(rb * 16 + h) * 12544 + win * 49) * 100;
  const unsigned short* rab = ra + tile_off;
  const unsigned short* uab = ug + tile_off;
  for (int i = tid; i < 1225; i += 256) {
    int n = i / 25, c = i % 25;
    u32x2 rv = *reinterpret_cast<const u32x2*>(&rab[n * 100 + c * 4]);
    if (FUSE) {
      u32x2 uv = *reinterpret_cast<const u32x2*>(&uab[n * 100 + c * 4]);
      unsigned short rr4[4] = {(unsigned short)(rv[0] & 0xffff), (unsigned short)(rv[0] >> 16),
                               (unsigned short)(rv[1] & 0xffff), (unsigned short)(rv[1] >> 16)};
      unsigned short uu4[4] = {(unsigned short)(uv[0] & 0xffff), (unsigned short)(uv[0] >> 16),
                               (unsigned short)(uv[1] & 0xffff), (unsigned short)(uv[1] >> 16)};
      unsigned short o4[4];
#pragma unroll
      for (int j = 0; j < 4; j++)
        o4[j] = f2bf(bf2f(rr4[j]) + gelu_f((bf2f(uu4[j]) - mu) * rstd));
      u32x2 w;
      w[0] = (unsigned int)o4[0] | ((unsigned int)o4[1] << 16);
      w[1] = (unsigned int)o4[2] | ((unsigned int)o4[3] << 16);
      *reinterpret_cast<u32x2*>(&P1[n * 136 + c * 4]) = w;
    } else {
      *reinterpret_cast<u32x2*>(&P1[n * 136 + c * 4]) = rv;
    }
  }
  for (int i = tid; i < 343; i += 256) {
    int n = i / 7, c = i % 7;
    *reinterpret_cast<u32x2*>(&P1[n * 136 + 100 + c * 4]) = zz;
  }
  __syncthreads();

  // ---- register softmax over 100 ref slots; store raw e, defer 1/l to qn epilogue ----
  if (tid < 196) {
    int n = tid >> 2, q = tid & 3;
    unsigned short* row = P1 + n * 136 + q * 25;
    float e[25];
#pragma unroll
    for (int r = 0; r < 25; r++) e[r] = bf2f(row[r]);
    float mx = -1e30f;
#pragma unroll
    for (int r = 0; r < 25; r++) mx = fmaxf(mx, e[r]);
    mx = fmaxf(mx, __shfl_xor(mx, 1));
    mx = fmaxf(mx, __shfl_xor(mx, 2));
    float sm = 0.f;
#pragma unroll
    for (int r = 0; r < 25; r++) { e[r] = __expf(e[r] - mx); sm += e[r]; }
    sm += __shfl_xor(sm, 1);
    sm += __shfl_xor(sm, 2);
#pragma unroll
    for (int r = 0; r < 25; r++) row[r] = f2bf(e[r]);
    if (q == 0) LSUM(n) = sm;
  }
  __syncthreads();

  // ---- qnew = P1 @ rvT^T  (M=64, N=32, K=128); rvT fragments direct from global ----
  const unsigned short* rvtg = refvT + (size_t)(rb * 16 + h) * 4096;   // 32 x 128, zero-padded
  f32x4 acc1[2] = {};
#pragma unroll
  for (int ks = 0; ks < 4; ks++) {
    short8 a = *reinterpret_cast<const short8*>(&P1[(wave * 16 + lrow) * 136 + ks * 32 + kq * 8]);
#pragma unroll
    for (int dt = 0; dt < 2; dt++) {
      short8 b = *reinterpret_cast<const short8*>(&rvtg[(dt * 16 + lrow) * 128 + ks * 32 + kq * 8]);
      acc1[dt] = __builtin_amdgcn_mfma_f32_16x16x32_bf16(a, b, acc1[dt], 0, 0, 0);
    }
  }
  float invl[4];
#pragma unroll
  for (int r = 0; r < 4; r++)
    invl[r] = 0.17677669529663688f / LSUM(wave * 16 + kq * 4 + r);
#pragma unroll
  for (int dt = 0; dt < 2; dt++)
#pragma unroll
    for (int r = 0; r < 4; r++) {
      int n = wave * 16 + kq * 4 + r;
      qn[n * 40 + dt * 16 + lrow] = f2bf(acc1[dt][r] * invl[r]);
    }
  __syncthreads();

  // ---- phase B: stage v^T (register transpose) into dead P1 space ----
  const unsigned short* kvb = kv + (size_t)b_ * 49 * 1024;
  for (int i = tid; i < 196; i += 256) {
    int m = i >> 2, dg = (i & 3) * 8;
    ushort8 vv = *reinterpret_cast<const ushort8*>(&kvb[m * 1024 + 512 + h * 32 + dg]);
#pragma unroll
    for (int j = 0; j < 8; j++) vT[(dg + j) * 72 + m] = vv[j];
  }
  for (int i = tid; i < 480; i += 256) vT[(i / 15) * 72 + 49 + i % 15] = 0;
  __syncthreads();

  // ---- logits = qn @ K^T (N=64, K=32); K fragments direct from global; +rpb+mask; softmax ----
  const unsigned short* bt = maskB + (size_t)win * 2744;
  const unsigned short* rt = rpbT + (size_t)h * 2744;
  short8 aq = *reinterpret_cast<const short8*>(&qn[(wave * 16 + lrow) * 40 + kq * 8]);
  f32x4 zero = {};
  float val[4][4];
#pragma unroll
  for (int mt = 0; mt < 4; mt++) {
    int mrow = mt * 16 + lrow;
    int mc = mrow < 49 ? mrow : 48;           // clamp: garbage masked below, stays in-buffer
    short8 bk = *reinterpret_cast<const short8*>(&kvb[mc * 1024 + h * 32 + kq * 8]);
    f32x4 lg = __builtin_amdgcn_mfma_f32_16x16x32_bf16(aq, bk, zero, 0, 0, 0);
    int m = mrow;
#pragma unroll
    for (int r = 0; r < 4; r++) {
      int n = wave * 16 + kq * 4 + r;
      float v;
      if (m < 49 && n < 49)
        v = lg[r] + bf2f(rt[n * 56 + m]) + bf2f(bt[n * 56 + m]);
      else v = -1e30f;
      val[mt][r] = v;
    }
  }
#pragma unroll
  for (int r = 0; r < 4; r++) {
    float mx = -1e30f;
#pragma unroll
    for (int mt = 0; mt < 4; mt++) mx = fmaxf(mx, val[mt][r]);
    mx = fmaxf(mx, __shfl_xor(mx, 1)); mx = fmaxf(mx, __shfl_xor(mx, 2));
    mx = fmaxf(mx, __shfl_xor(mx, 4)); mx = fmaxf(mx, __shfl_xor(mx, 8));
    float sm = 0.f, e[4];
#pragma unroll
    for (int mt = 0; mt < 4; mt++) { e[mt] = __expf(val[mt][r] - mx); sm += e[mt]; }
    sm += __shfl_xor(sm, 1); sm += __shfl_xor(sm, 2);
    sm += __shfl_xor(sm, 4); sm += __shfl_xor(sm, 8);
    float inv = 1.f / sm;
    int n = wave * 16 + kq * 4 + r;
#pragma unroll
    for (int mt = 0; mt < 4; mt++) P2[n * 72 + mt * 16 + lrow] = f2bf(e[mt] * inv);
  }
  __syncthreads();

  // ---- out = P2 @ vT^T (N=32, K=64) -> global bf16 ----
  f32x4 acc2[2] = {};
#pragma unroll
  for (int ks = 0; ks < 2; ks++) {
    short8 ap = *reinterpret_cast<const short8*>(&P2[(wave * 16 + lrow) * 72 + ks * 32 + kq * 8]);
#pragma unroll
    for (int dt = 0; dt < 2; dt++) {
      short8 bv = *reinterpret_cast<const short8*>(&vT[(dt * 16 + lrow) * 72 + ks * 32 + kq * 8]);
      acc2[dt] = __builtin_amdgcn_mfma_f32_16x16x32_bf16(ap, bv, acc2[dt], 0, 0, 0);
    }
  }
  unsigned short* ab = att + (size_t)b_ * 49 * 512 + h * 32;
#pragma unroll
  for (int dt = 0; dt < 2; dt++)
#pragma unroll
    for (int r = 0; r < 4; r++) {
      int n = wave * 16 + kq * 4 + r;
      if (n < 49) ab[n * 512 + dt * 16 + lrow] = f2bf(acc2[dt][r]);
    }
#undef LSUM
}

// ---------------- window-reverse gather + residual + LN2 (wave-per-row) ----------------
__global__ __launch_bounds__(256) void resid_ln2_kernel(
    const float* __restrict__ x, const __hip_bfloat16* __restrict__ proj_out,
    const float* __restrict__ w2, const float* __restrict__ b2,
    float* __restrict__ out, __hip_bfloat16* __restrict__ hout) {
  int tid = threadIdx.x;
  int wave = tid >> 6, lane = tid & 63;
  int blk = blockIdx.x * 4 + wave;    // b*12544 + l
  int bb = blk / 12544, l = blk % 12544;
  int hh = l / 112, ww = l % 112;
  int hs = (hh + 109) % 112, wsx = (ww + 109) % 112;   // (h-3) mod 112
  int t = (bb * 256 + (hs / 7) * 16 + (wsx / 7)) * 49 + (hs % 7) * 7 + (wsx % 7);
  const float* xr = x + (size_t)blk * 512 + lane * 8;
  const unsigned short* pr = (const unsigned short*)proj_out + (size_t)t * 512 + lane * 8;
  f32x4 x0 = *reinterpret_cast<const f32x4*>(xr);
  f32x4 x1 = *reinterpret_cast<const f32x4*>(xr + 4);
  ushort8 p8 = *reinterpret_cast<const ushort8*>(pr);
  float v[8];
#pragma unroll
  for (int j = 0; j < 4; j++) {
    v[j]     = x0[j] + bf2f(p8[j]);
    v[4 + j] = x1[j] + bf2f(p8[4 + j]);
  }
  float s = 0.f, s2 = 0.f;
#pragma unroll
  for (int j = 0; j < 8; j++) { s += v[j]; s2 += v[j] * v[j]; }
  float* orow = out + (size_t)blk * 512 + lane * 8;
  f32x4 o0, o1;
#pragma unroll
  for (int j = 0; j < 4; j++) { o0[j] = v[j]; o1[j] = v[4 + j]; }
  *reinterpret_cast<f32x4*>(orow) = o0;
  *reinterpret_cast<f32x4*>(orow + 4) = o1;
#pragma unroll
  for (int o = 1; o < 64; o <<= 1) { s += __shfl_xor(s, o); s2 += __shfl_xor(s2, o); }
  float mu = s * (1.f / 512.f);
  float rstd = rsqrtf(s2 * (1.f / 512.f) - mu * mu + 1e-5f);
  f32x4 w0 = *reinterpret_cast<const f32x4*>(&w2[lane * 8]);
  f32x4 w1 = *reinterpret_cast<const f32x4*>(&w2[lane * 8 + 4]);
  f32x4 c0 = *reinterpret_cast<const f32x4*>(&b2[lane * 8]);
  f32x4 c1 = *reinterpret_cast<const f32x4*>(&b2[lane * 8 + 4]);
  ushort8 h8;
#pragma unroll
  for (int j = 0; j < 4; j++) {
    h8[j]     = f2bf((v[j] - mu) * rstd * w0[j] + c0[j]);
    h8[4 + j] = f2bf((v[4 + j] - mu) * rstd * w1[j] + c1[j]);
  }
  *reinterpret_cast<ushort8*>((unsigned short*)hout + (size_t)blk * 512 + lane * 8) = h8;
}

// =======================================================================
extern "C" void kernel_launch(void* const* d_in, const int* in_sizes, int n_in,
                              void* d_out, int out_size, void* d_ws, size_t ws_size,
                              hipStream_t stream) {
  const float* x       = (const float*)d_in[0];
  const float* x_ref   = (const float*)d_in[1];
  const float* mask    = (const float*)d_in[2];
  const float* n1w     = (const float*)d_in[3];
  const float* n1b     = (const float*)d_in[4];
  const float* qkv_w   = (const float*)d_in[5];
  const float* qkv_b   = (const float*)d_in[6];
  const float* diff_mu = (const float*)d_in[7];
  const float* diff_ls = (const float*)d_in[8];
  const float* rpb     = (const float*)d_in[9];
  const float* ref_w   = (const float*)d_in[10];
  const float* ref_b   = (const float*)d_in[11];
  const float* conv_w  = (const float*)d_in[12];
  const float* conv_b  = (const float*)d_in[13];
  const float* proj_w  = (const float*)d_in[14];
  const float* proj_b  = (const float*)d_in[15];
  const float* n2w     = (const float*)d_in[16];
  const float* n2b     = (const float*)d_in[17];
  const float* fc1_w   = (const float*)d_in[18];
  const float* fc1_b   = (const float*)d_in[19];
  const float* fc2_w   = (const float*)d_in[20];
  const float* fc2_b   = (const float*)d_in[21];
  float* out = (float*)d_out;

  char* ws = (char*)d_ws;
  size_t off = 0;
  auto alloc = [&](size_t bytes) -> char* {
    char* p = ws + off;
    off += (bytes + 255) & ~(size_t)255;
    return p;
  };
  // ---- persistent small buffers ----
  __hip_bfloat16* wq_bf = (__hip_bfloat16*)alloc(1536ULL * 512 * 2);   // q rows 0..511, kv rows 512..1535
  __hip_bfloat16* wp_bf = (__hip_bfloat16*)alloc(512ULL * 512 * 2);
  __hip_bfloat16* w1_bf = (__hip_bfloat16*)alloc(2048ULL * 512 * 2);
  __hip_bfloat16* w2_bf = (__hip_bfloat16*)alloc(512ULL * 2048 * 2);
  unsigned short* refq  = (unsigned short*)alloc(2ULL * 16 * 100 * 32 * 2);
  unsigned short* refvT = (unsigned short*)alloc(2ULL * 16 * 32 * 128 * 2);  // stride-128 padded
  unsigned short* maskB = (unsigned short*)alloc(256ULL * 49 * 56 * 2);
  unsigned short* rpbT  = (unsigned short*)alloc(16ULL * 49 * 56 * 2);
  unsigned short* cwT   = (unsigned short*)alloc(2560ULL * 2);            // conv weight fragments
  float* psum  = (float*)alloc(2ULL * 3136 * 16 * 4);
  float* psumq = (float*)alloc(2ULL * 3136 * 16 * 4);
  float* stats = (float*)alloc(64 * 4);
  // ---- aliased regions ----
  char* regX  = alloc(25088ULL * 512 * 2);      // xw_bf -> att_bf            (25.7 MB)
  char* regQ  = alloc(25088ULL * 512 * 2);      // q_bf  -> h_bf              (25.7 MB)
  char* regRA = alloc(2ULL * 16 * 12544 * 100 * 2);  // ra    -> hg (per-chunk) (80.3 MB)
  char* regU  = alloc(2ULL * 16 * 12544 * 100 * 2);  // u -> (kv_bf) + proj_bf  (80.3 MB)

  __hip_bfloat16* xw_bf   = (__hip_bfloat16*)regX;
  __hip_bfloat16* att_bf  = (__hip_bfloat16*)regX;                      // after attn
  __hip_bfloat16* q_bf    = (__hip_bfloat16*)regQ;
  __hip_bfloat16* h_bf    = (__hip_bfloat16*)regQ;                      // after ra_kernel
  __hip_bfloat16* ra      = (__hip_bfloat16*)regRA;
  __hip_bfloat16* hg      = (__hip_bfloat16*)regRA;                     // after attn (51.4MB/chunk)
  __hip_bfloat16* u       = (__hip_bfloat16*)regU;
  __hip_bfloat16* proj_bf = (__hip_bfloat16*)(regU + 51380224);         // after attn (25.7MB)

  // fused path needs u live through attn -> kv in a dedicated region if ws allows
  const size_t kv_bytes = 25088ULL * 1024 * 2;   // 51.4 MB
  bool fused = (ws_size >= off + kv_bytes);
  __hip_bfloat16* kv_bf = fused ? (__hip_bfloat16*)alloc(kv_bytes)
                                : (__hip_bfloat16*)regU;   // classic: aliases dead u

  // 1. weights -> bf16 (single vectorized dispatch) ; bias tables
  f2b_all_kernel<<<1536, 256, 0, stream>>>(qkv_w, proj_w, fc1_w, fc2_w,
                                           wq_bf, wp_bf, w1_bf, w2_bf);
  maskb_kernel<<<2744, 256, 0, stream>>>(mask, maskB);
  rpbt_kernel<<<172, 256, 0, stream>>>(rpb, rpbT);
  cwt_kernel<<<10, 256, 0, stream>>>(conv_w, cwT);
  // 2. LN1 + shift + window partition (wave-per-row)
  ln1_window_kernel<<<6272, 256, 0, stream>>>(x, n1w, n1b, xw_bf);
  // 3. q/kv projection
  if (fused) {
    // merged qkv GEMM: one A staging pass, outputs routed to q_bf / kv_bf (layouts unchanged)
    gemm_bt<4><<<2352, 256, 0, stream>>>(xw_bf, wq_bf, qkv_b, (float*)kv_bf, q_bf,
                                         25088, 1536, 512);
  } else {
    gemm_bt<1><<<784, 256, 0, stream>>>(xw_bf, wq_bf, qkv_b, nullptr, q_bf,
                                        25088, 512, 512);
  }
  // 4. reference tokens
  ref_kernel<<<200, 256, 0, stream>>>(x_ref, ref_w, ref_b, diff_mu, diff_ls, refq, refvT);
  // 5. ra = q @ ref_q^T (MFMA, XCD-chunked)
  ra_kernel<<<8192, 256, 0, stream>>>(q_bf, refq, ra);
  // 6. conv diffusion x3 (apply of round 3 folded into attn when fused)
  for (int rd = 0; rd < 3; rd++) {
    conv_kernel<<<dim3(3136, 2), 256, 0, stream>>>(ra, cwT, conv_b, u, psum, psumq);
    conv_stats_kernel<<<32, 256, 0, stream>>>(psum, psumq, stats);
    if (rd < 2 || !fused)
      conv_apply_kernel<<<4096, 256, 0, stream>>>(ra, u, stats);
  }
  // 7. classic path: kv GEMM into dead-u alias (fused path did it in step 3)
  if (!fused)
    gemm_bt<1><<<1568, 256, 0, stream>>>(xw_bf, wq_bf + 512 * 512, qkv_b + 512,
                                         nullptr, kv_bf, 25088, 1024, 512);
  // 8. fused MFMA attention (xw dead -> att_bf; XCD-chunked)
  if (fused)
    attn_kernel<1><<<8192, 256, 0, stream>>>(ra, u, stats, refvT, kv_bf, rpbT, maskB, att_bf);
  else
    attn_kernel<0><<<8192, 256, 0, stream>>>(ra, u, stats, refvT, kv_bf, rpbT, maskB, att_bf);
  // 9. proj GEMM (bias -> bf16, into regU tail; u dead after attn)
  gemm_bt<1><<<784, 256, 0, stream>>>(att_bf, wp_bf, proj_b, nullptr, proj_bf,
                                      25088, 512, 512);
  // 10. window reverse + residual + LN2 (wave-per-row; h_bf into dead q region)
  resid_ln2_kernel<<<6272, 256, 0, stream>>>(x, proj_bf, n2w, n2b, out, h_bf);
  // 11. MLP in two M-chunks; hg reuses dead ra region
  for (int ch = 0; ch < 2; ch++) {
    const __hip_bfloat16* hA = h_bf + (size_t)ch * 12544 * 512;
    gemm_bt<2><<<1568, 256, 0, stream>>>(hA, w1_bf, fc1_b, nullptr, hg,
                                         12544, 2048, 512);
    gemm_bt<3><<<392, 256, 0, stream>>>(hg, w2_bf, fc2_b,
                                        out + (size_t)ch * 12544 * 512, nullptr,
                                        12544, 512, 2048);
  }
}

// Round 10
// 1008.428 us; speedup vs baseline: 1.1202x; 1.0777x over previous
//
#include <hip/hip_runtime.h>
#include <hip/hip_bf16.h>

typedef __attribute__((ext_vector_type(8))) short short8;        // 8 bf16 = 4 VGPRs
typedef __attribute__((ext_vector_type(8))) unsigned short ushort8;
typedef __attribute__((ext_vector_type(4))) float f32x4;
typedef __attribute__((ext_vector_type(4))) unsigned int u32x4;
typedef __attribute__((ext_vector_type(2))) unsigned int u32x2;

#define DEV __device__ __forceinline__

DEV float gelu_f(float x) { return 0.5f * x * (1.f + erff(x * 0.70710678118654752440f)); }

DEV float bf2f(unsigned short s) {
  unsigned int t = ((unsigned int)s) << 16;
  float f; __builtin_memcpy(&f, &t, 4); return f;
}
DEV unsigned short f2bf(float f) {
  __hip_bfloat16 b = __float2bfloat16(f);
  unsigned short s; __builtin_memcpy(&s, &b, 2); return s;
}

// async global->LDS 16B/lane (dest = wave-uniform base + lane*16)
DEV void async_copy16(void* lds, const void* g) {
  __builtin_amdgcn_global_load_lds(
      (const __attribute__((address_space(1))) unsigned int*)g,
      (__attribute__((address_space(3))) unsigned int*)lds, 16, 0, 0);
}

// block-wide (256 thr) sum of two values; every thread gets the totals
DEV void block_reduce2(float& s, float& s2) {
  __shared__ float red[8];
  int tid = threadIdx.x;
#pragma unroll
  for (int o = 32; o > 0; o >>= 1) { s += __shfl_down(s, o); s2 += __shfl_down(s2, o); }
  if ((tid & 63) == 0) { red[tid >> 6] = s; red[4 + (tid >> 6)] = s2; }
  __syncthreads();
  s  = red[0] + red[1] + red[2] + red[3];
  s2 = red[4] + red[5] + red[6] + red[7];
}

// ---------------- all four weight tensors fp32 -> bf16, one dispatch, vectorized ----------------
__global__ __launch_bounds__(256) void f2b_all_kernel(
    const float* __restrict__ qkv_w, const float* __restrict__ proj_w,
    const float* __restrict__ fc1_w, const float* __restrict__ fc2_w,
    __hip_bfloat16* __restrict__ wq, __hip_bfloat16* __restrict__ wp,
    __hip_bfloat16* __restrict__ w1, __hip_bfloat16* __restrict__ w2) {
  int i = blockIdx.x * 256 + threadIdx.x;          // unit = 8 elems; total 393216 units
  const float* src; unsigned short* dst; int o;
  if (i < 98304)       { src = qkv_w;  dst = (unsigned short*)wq; o = i; }
  else if (i < 131072) { src = proj_w; dst = (unsigned short*)wp; o = i - 98304; }
  else if (i < 262144) { src = fc1_w;  dst = (unsigned short*)w1; o = i - 131072; }
  else                 { src = fc2_w;  dst = (unsigned short*)w2; o = i - 262144; }
  f32x4 a = *reinterpret_cast<const f32x4*>(&src[(size_t)o * 8]);
  f32x4 b = *reinterpret_cast<const f32x4*>(&src[(size_t)o * 8 + 4]);
  ushort8 v;
#pragma unroll
  for (int j = 0; j < 4; j++) { v[j] = f2bf(a[j]); v[4 + j] = f2bf(b[j]); }
  *reinterpret_cast<ushort8*>(&dst[(size_t)o * 8]) = v;
}

// ---------------- mask -> bf16 padded [win][49][56] ----------------
__global__ __launch_bounds__(256) void maskb_kernel(const float* __restrict__ mask,
                                                    unsigned short* __restrict__ maskB) {
  int i = blockIdx.x * 256 + threadIdx.x;          // 256*49*56 = 702464 exactly
  int m = i % 56, rest = i / 56;
  int n = rest % 49, win = rest / 49;
  unsigned short v = 0;
  if (m < 49) v = f2bf(mask[((size_t)win * 49 + n) * 49 + m]);
  maskB[i] = v;
}

// ---------------- rpb -> bf16 padded [h][49][56] ----------------
__global__ __launch_bounds__(256) void rpbt_kernel(const float* __restrict__ rpb,
                                                   unsigned short* __restrict__ rpbT) {
  int i = blockIdx.x * 256 + threadIdx.x;          // 16*49*56 = 43904
  if (i >= 43904) return;
  int m = i % 56, rest = i / 56;
  int n = rest % 49, h = rest / 49;
  unsigned short v = 0;
  if (m < 49) {
    int rp = (n / 7 - m / 7 + 6) * 13 + (n % 7 - m % 7 + 6);
    v = f2bf(rpb[rp * 16 + h]);
  }
  rpbT[i] = v;
}

// ---------------- conv weight fragment table [co=16][160] (shared by all conv blocks) ----------------
__global__ __launch_bounds__(256) void cwt_kernel(const float* __restrict__ cw,
                                                  unsigned short* __restrict__ cwT) {
  int i = blockIdx.x * 256 + threadIdx.x;          // 2560
  if (i >= 2560) return;
  int co = i / 160, k = i % 160;
  unsigned short v = 0;
  if (k < 144) {
    int ci = k & 15, p = k >> 4;
    v = f2bf(cw[(co * 16 + ci) * 9 + p]);
  }
  cwT[i] = v;
}

// ---------------- LN1 + cyclic shift + window partition -> bf16 (wave-per-row) ----------------
__global__ __launch_bounds__(256) void ln1_window_kernel(
    const float* __restrict__ x, const float* __restrict__ w, const float* __restrict__ b,
    __hip_bfloat16* __restrict__ xw) {
  int tid = threadIdx.x;
  int wave = tid >> 6, lane = tid & 63;
  int t = blockIdx.x * 4 + wave;      // 0..25087
  int b_ = t / 49, n = t % 49;
  int bb = b_ >> 8, win = b_ & 255;
  int wi = win >> 4, wj = win & 15;
  int ii = n / 7, jj = n % 7;
  int sh = (wi * 7 + ii + 3) % 112;
  int sw = (wj * 7 + jj + 3) % 112;
  const float* row = x + ((size_t)bb * 12544 + sh * 112 + sw) * 512;
  f32x4 v0 = *reinterpret_cast<const f32x4*>(&row[lane * 8]);
  f32x4 v1 = *reinterpret_cast<const f32x4*>(&row[lane * 8 + 4]);
  float s = 0.f, s2 = 0.f;
#pragma unroll
  for (int j = 0; j < 4; j++) {
    s += v0[j] + v1[j];
    s2 += v0[j] * v0[j] + v1[j] * v1[j];
  }
#pragma unroll
  for (int o = 1; o < 64; o <<= 1) { s += __shfl_xor(s, o); s2 += __shfl_xor(s2, o); }
  float mu = s * (1.f / 512.f);
  float rstd = rsqrtf(s2 * (1.f / 512.f) - mu * mu + 1e-5f);
  f32x4 w0 = *reinterpret_cast<const f32x4*>(&w[lane * 8]);
  f32x4 w1 = *reinterpret_cast<const f32x4*>(&w[lane * 8 + 4]);
  f32x4 c0 = *reinterpret_cast<const f32x4*>(&b[lane * 8]);
  f32x4 c1 = *reinterpret_cast<const f32x4*>(&b[lane * 8 + 4]);
  ushort8 o8;
#pragma unroll
  for (int j = 0; j < 4; j++) {
    o8[j]     = f2bf((v0[j] - mu) * rstd * w0[j] + c0[j]);
    o8[4 + j] = f2bf((v1[j] - mu) * rstd * w1[j] + c1[j]);
  }
  *reinterpret_cast<ushort8*>((unsigned short*)xw + (size_t)t * 512 + lane * 8) = o8;
}

// ---------------- bf16 MFMA GEMM v3: 64x128 tile, 24KB LDS -> 6 blocks/CU ----------------
// Previous 128x128/64KB variants all pinned at ~84us with 2 resident blocks (2 instruction
// streams can't hide ~900cy load latency over ~160cy of MFMA). 64x128 single-buffered gives
// 6 independent block streams/CU (the same lever that paid on attn 4->8 and conv 4->6).
// EPI: 1 = bias -> bf16 ; 2 = bias+gelu -> bf16 ; 3 = bias -> f32 += ;
//      4 = merged qkv: col<512 -> q_bf (stride 512), col>=512 -> kv_bf (stride 1024)
// Grid = (M/64)*(N/128), 1-D, bijective XCD swizzle (n fastest -> A panel L2-hot).
template <int EPI>
__global__ __launch_bounds__(256, 6) void gemm_bt(
    const __hip_bfloat16* __restrict__ A, const __hip_bfloat16* __restrict__ B,
    const float* __restrict__ bias, float* __restrict__ outF,
    __hip_bfloat16* __restrict__ outB, int M, int N, int K) {
  __shared__ __align__(16) __hip_bfloat16 As[64 * 64];    //  8 KB
  __shared__ __align__(16) __hip_bfloat16 Bs[128 * 64];   // 16 KB
  int nn = N >> 7;
  int nblk = gridDim.x;
  int bid = blockIdx.x;
  int xcd = bid & 7, slot = bid >> 3;
  int q8 = nblk >> 3, r8 = nblk & 7;
  int base = xcd < r8 ? xcd * (q8 + 1) : r8 * (q8 + 1) + (xcd - r8) * q8;
  int lin = base + slot;              // bijective; n fastest
  int m0 = (lin / nn) << 6, n0 = (lin % nn) << 7;
  int tid = threadIdx.x;
  int wave = tid >> 6, lane = tid & 63;
  int wr = (wave >> 1) * 32, wc = (wave & 1) * 64;   // 2x2 wave grid, 32x64 per wave
  int lrow = lane & 15, kq = lane >> 4;
  int srow = lane >> 3, scol = (lane & 7) * 8;       // staging: 8 rows x 64 cols per wave-inst
  const __hip_bfloat16* Abase = A + (size_t)m0 * K;
  const __hip_bfloat16* Bbase = B + (size_t)n0 * K;
  f32x4 acc[2][4] = {};
  for (int k0 = 0; k0 < K; k0 += 64) {
#pragma unroll
    for (int i = 0; i < 2; i++) {
      int row = wave * 16 + i * 8;
      async_copy16(&As[row * 64], &Abase[(size_t)(row + srow) * K + k0 + scol]);
    }
#pragma unroll
    for (int i = 0; i < 4; i++) {
      int row = wave * 32 + i * 8;
      async_copy16(&Bs[row * 64], &Bbase[(size_t)(row + srow) * K + k0 + scol]);
    }
    __syncthreads();
#pragma unroll
    for (int ks = 0; ks < 2; ks++) {
      short8 af[2], bf[4];
#pragma unroll
      for (int t = 0; t < 2; t++)
        af[t] = *reinterpret_cast<const short8*>(&As[(wr + t * 16 + lrow) * 64 + ks * 32 + kq * 8]);
#pragma unroll
      for (int t = 0; t < 4; t++)
        bf[t] = *reinterpret_cast<const short8*>(&Bs[(wc + t * 16 + lrow) * 64 + ks * 32 + kq * 8]);
#pragma unroll
      for (int tm = 0; tm < 2; tm++)
#pragma unroll
        for (int tn = 0; tn < 4; tn++)
          acc[tm][tn] = __builtin_amdgcn_mfma_f32_16x16x32_bf16(af[tm], bf[tn], acc[tm][tn], 0, 0, 0);
    }
    __syncthreads();
  }
  // D: row=(lane>>4)*4+r, col=lane&15 (verified gfx950 C/D layout)
#pragma unroll
  for (int tm = 0; tm < 2; tm++) {
#pragma unroll
    for (int tn = 0; tn < 4; tn++) {
      int col = n0 + wc + tn * 16 + lrow;
      float bv = bias[col];
#pragma unroll
      for (int r = 0; r < 4; r++) {
        int row = m0 + wr + tm * 16 + kq * 4 + r;
        float v = acc[tm][tn][r] + bv;
        if (EPI == 4) {
          if (col < 512)
            ((unsigned short*)outB)[(size_t)row * 512 + col] = f2bf(v);
          else
            ((unsigned short*)outF)[(size_t)row * 1024 + (col - 512)] = f2bf(v);
        } else {
          size_t o = (size_t)row * N + col;
          if (EPI == 1) outB[o] = __float2bfloat16(v);
          else if (EPI == 2) outB[o] = __float2bfloat16(gelu_f(v));
          else outF[o] += v;
        }
      }
    }
  }
}

// ---------------- reference-token projection (tiny); refvT padded to stride 128 ----------------
__global__ __launch_bounds__(256) void ref_kernel(
    const float* __restrict__ x_ref, const float* __restrict__ w, const float* __restrict__ bias,
    const float* __restrict__ diff_mu, const float* __restrict__ diff_ls,
    unsigned short* __restrict__ refq, unsigned short* __restrict__ refvT) {
  int blk = blockIdx.x;               // 0..199
  int b = blk / 100, r = blk % 100;
  __shared__ float xs[512];
  int tid = threadIdx.x;
  const float* xr = x_ref + (size_t)(b * 100 + r) * 512;
  xs[tid] = xr[tid];
  xs[tid + 256] = xr[tid + 256];
  __syncthreads();
#pragma unroll
  for (int cc = 0; cc < 4; cc++) {
    int c = cc * 256 + tid;
    const float* wr = w + (size_t)c * 512;
    float s = bias[c];
    for (int k = 0; k < 512; k++) s += xs[k] * wr[k];
    if (c < 512) {
      float v = diff_mu[c] + expf(diff_ls[c]) * s;
      int hh = c >> 5, d = c & 31;
      refq[((size_t)(b * 16 + hh) * 100 + r) * 32 + d] = f2bf(v);
    } else {
      int c2 = c - 512, hh = c2 >> 5, d = c2 & 31;
      refvT[(((size_t)b * 16 + hh) * 32 + d) * 128 + r] = f2bf(s);
    }
  }
  // zero-fill pad cols 100..127 (28 pad cols; blocks r<28 each own one column)
  if (r < 28) {
#pragma unroll
    for (int j = 0; j < 2; j++) {
      int idx = j * 256 + tid;          // 0..511 = (hh, d)
      int hh = idx >> 5, d = idx & 31;
      refvT[(((size_t)b * 16 + hh) * 32 + d) * 128 + 100 + r] = 0;
    }
  }
}

// ---------------- ra = q @ ref_q^T ; MFMA ; block per (b_, head) ----------------
// XCD-chunked blk: the 16 head-blocks of a window share the q tile -> same-XCD L2.
__global__ __launch_bounds__(256) void ra_kernel(
    const __hip_bfloat16* __restrict__ q, const unsigned short* __restrict__ refq,
    __hip_bfloat16* __restrict__ ra) {
  __shared__ __align__(16) unsigned short q_s[64 * 40];
  __shared__ __align__(16) unsigned short rq_s[112 * 40];
  int bid = blockIdx.x;               // 8192 (%8==0 -> bijective chunking)
  int blk = (bid & 7) * 1024 + (bid >> 3);
  int b_ = blk >> 4, h = blk & 15;
  int rb = b_ >> 8, win = b_ & 255;
  int tid = threadIdx.x;
  int wave = tid >> 6, lane = tid & 63;
  int lrow = lane & 15, kq = lane >> 4;
  u32x4 z4 = {};
  const unsigned short* qb = (const unsigned short*)q + (size_t)b_ * 49 * 512 + h * 32;
  for (int i = tid; i < 196; i += 256) {
    int n = i >> 2, c = i & 3;
    *reinterpret_cast<u32x4*>(&q_s[n * 40 + c * 8]) =
        *reinterpret_cast<const u32x4*>(&qb[n * 512 + c * 8]);
  }
  for (int i = tid; i < 60; i += 256) {
    int n = 49 + (i >> 2), c = i & 3;
    *reinterpret_cast<u32x4*>(&q_s[n * 40 + c * 8]) = z4;
  }
  const unsigned short* rqg = refq + (size_t)(rb * 16 + h) * 3200;
  for (int i = tid; i < 400; i += 256) {
    int r = i >> 2, c = i & 3;
    *reinterpret_cast<u32x4*>(&rq_s[r * 40 + c * 8]) =
        *reinterpret_cast<const u32x4*>(&rqg[r * 32 + c * 8]);
  }
  for (int i = tid; i < 48; i += 256) {
    int r = 100 + (i >> 2), c = i & 3;
    *reinterpret_cast<u32x4*>(&rq_s[r * 40 + c * 8]) = z4;
  }
  __syncthreads();
  short8 a = *reinterpret_cast<const short8*>(&q_s[(wave * 16 + lrow) * 40 + kq * 8]);
  unsigned short* ra_base = (unsigned short*)ra + ((size_t)(rb * 16 + h) * 12544 + win * 49) * 100;
  f32x4 zero = {};
#pragma unroll
  for (int nt = 0; nt < 7; nt++) {
    short8 b = *reinterpret_cast<const short8*>(&rq_s[(nt * 16 + lrow) * 40 + kq * 8]);
    f32x4 c = __builtin_amdgcn_mfma_f32_16x16x32_bf16(a, b, zero, 0, 0, 0);
    int col = nt * 16 + lrow;
#pragma unroll
    for (int r = 0; r < 4; r++) {
      int n = wave * 16 + kq * 4 + r;
      if (n < 49 && col < 100) ra_base[n * 100 + col] = f2bf(c[r]);
    }
  }
}

// ---------------- implicit-GEMM MFMA conv v6: LDS-staged coalesced u stores ----------------
// XCD-chunked yt: neighbor row-tiles (sharing halo rows + streaming adjacent ra/u) stay on
// one XCD's L2.
DEV int swzi(int pl, int ci) {
  int byte = (pl << 5) + (ci << 1);
  byte ^= ((pl >> 2) & 3) << 4;
  return byte >> 1;                   // ushort index
}
__global__ __launch_bounds__(256, 6) void conv_kernel(
    const __hip_bfloat16* __restrict__ ra_, const unsigned short* __restrict__ cwT,
    const float* __restrict__ cb,
    __hip_bfloat16* __restrict__ u_, float* __restrict__ psum, float* __restrict__ psumsq) {
  __shared__ __align__(16) unsigned short in_s[6 * 103 * 16];    // 19,776 B swizzled
  __shared__ __align__(16) unsigned short st_s[4 * 16 * 36];     //  4,608 B (stride 36 spreads banks)
  __shared__ float sred_s[4][16], sred_s2[4][16];
  const unsigned short* ra = (const unsigned short*)ra_;
  unsigned short* u = (unsigned short*)u_;
  int ytb = blockIdx.x;               // 3136 (%8==0)
  int yt = (ytb & 7) * 392 + (ytb >> 3);
  int bb = blockIdx.y;
  int y0 = yt * 4;
  int tid = threadIdx.x;
  int wave = tid >> 6, lane = tid & 63;
  int lrow = lane & 15, kq = lane >> 4;
  for (int i = tid; i < 288; i += 256) {
    int ci = i & 15, rem = i >> 4;
    int yl = rem / 3, xs = rem % 3;
    int xl = (xs == 0) ? 0 : (100 + xs);
    in_s[swzi(yl * 103 + xl, ci)] = 0;
  }
  if (tid < 192) {
    int unit = tid >> 1, par = tid & 1;
    int ci = unit / 6, yl = unit % 6;
    int gy = y0 - 1 + yl;
    bool rv = (gy >= 0 && gy < 12544);
    const unsigned short* rp = ra + (((size_t)bb * 16 + ci) * 12544 + (rv ? gy : 0)) * 100;
    int plb = yl * 103 + 1;
#pragma unroll 4
    for (int c = par; c < 25; c += 2) {
      u32x2 d = {0u, 0u};
      if (rv) d = *reinterpret_cast<const u32x2*>(&rp[c * 4]);
      int pl = plb + c * 4;
      in_s[swzi(pl + 0, ci)] = (unsigned short)(d[0] & 0xffff);
      in_s[swzi(pl + 1, ci)] = (unsigned short)(d[0] >> 16);
      in_s[swzi(pl + 2, ci)] = (unsigned short)(d[1] & 0xffff);
      in_s[swzi(pl + 3, ci)] = (unsigned short)(d[1] >> 16);
    }
  }
  __syncthreads();

  short8 afr[5];
#pragma unroll
  for (int c = 0; c < 5; c++)
    afr[c] = *reinterpret_cast<const short8*>(&cwT[lrow * 160 + c * 32 + kq * 8]);
  int kqh = kq >> 1, ci0 = (kq & 1) * 8;
  int kyA[5], kxA[5];
#pragma unroll
  for (int c = 0; c < 5; c++) {
    int p = c * 2 + kqh; if (p > 8) p = 0;
    kyA[c] = p / 3; kxA[c] = p % 3;
  }
  float bias_r[4];
#pragma unroll
  for (int r = 0; r < 4; r++) bias_r[r] = cb[kq * 4 + r];
  float s_r[4] = {0.f, 0.f, 0.f, 0.f}, s2_r[4] = {0.f, 0.f, 0.f, 0.f};

  int yl = wave;
  int gy = y0 + yl;
  unsigned short* stw = &st_s[wave * 16 * 36];
  int seg = lane >> 2, part = lane & 3;
  const size_t ubase = ((size_t)bb * 16 * 12544 + gy) * 100;   // + ch*12544*100 + px
#pragma unroll
  for (int xp = 0; xp < 4; xp++) {
#pragma unroll
    for (int xh = 0; xh < 2; xh++) {
      int xg = xp * 2 + xh;
      if (xg >= 7) break;
      int px = xg * 16 + lrow;
      int pxc = px < 100 ? px : 99;
      f32x4 acc = {};
#pragma unroll
      for (int c = 0; c < 5; c++) {
        short8 bfrag = *reinterpret_cast<const short8*>(
            &in_s[swzi((yl + kyA[c]) * 103 + pxc + kxA[c], ci0)]);
        acc = __builtin_amdgcn_mfma_f32_16x16x32_bf16(afr[c], bfrag, acc, 0, 0, 0);
      }
      bool valid = px < 100;
#pragma unroll
      for (int r = 0; r < 4; r++) {
        float v = acc[r] + bias_r[r];
        if (valid) {
          stw[(kq * 4 + r) * 36 + xh * 16 + lrow] = f2bf(v);
          s_r[r] += v; s2_r[r] += v * v;
        }
      }
    }
    // wave-synchronous coalesced store of the staged 16ch x 32px tile
    unsigned short* ug = u + ubase + (size_t)seg * 1254400;    // 12544*100
    if (xp < 3) {
      u32x2 d0 = *reinterpret_cast<const u32x2*>(&stw[seg * 36 + part * 4]);
      u32x2 d1 = *reinterpret_cast<const u32x2*>(&stw[seg * 36 + 16 + part * 4]);
      *reinterpret_cast<u32x2*>(&ug[xp * 32 + part * 4]) = d0;        // bytes 0..31 of chunk
      *reinterpret_cast<u32x2*>(&ug[xp * 32 + 16 + part * 4]) = d1;   // bytes 32..63
    } else if (lane < 16) {
      u32x2 d = *reinterpret_cast<const u32x2*>(&st_s[wave * 16 * 36 + lane * 36]);
      *reinterpret_cast<u32x2*>(&u[ubase + (size_t)lane * 1254400 + 96]) = d;
    }
  }
#pragma unroll
  for (int o = 1; o < 16; o <<= 1)
#pragma unroll
    for (int r = 0; r < 4; r++) { s_r[r] += __shfl_xor(s_r[r], o); s2_r[r] += __shfl_xor(s2_r[r], o); }
  if (lrow == 0)
#pragma unroll
    for (int r = 0; r < 4; r++) { sred_s[wave][kq * 4 + r] = s_r[r]; sred_s2[wave][kq * 4 + r] = s2_r[r]; }
  __syncthreads();
  if (tid < 16) {
    float s  = sred_s[0][tid] + sred_s[1][tid] + sred_s[2][tid] + sred_s[3][tid];
    float s2 = sred_s2[0][tid] + sred_s2[1][tid] + sred_s2[2][tid] + sred_s2[3][tid];
    size_t pi = ((size_t)bb * 3136 + yt) * 16 + tid;
    psum[pi] = s; psumsq[pi] = s2;
  }
}

__global__ __launch_bounds__(256) void conv_stats_kernel(
    const float* __restrict__ psum, const float* __restrict__ psumsq, float* __restrict__ stats) {
  int g = blockIdx.x;                 // 32 = (b, co)
  int bb = g >> 4, co = g & 15;
  int tid = threadIdx.x;
  float s = 0.f, s2 = 0.f;
  for (int t = tid; t < 3136; t += 256) {
    size_t pi = ((size_t)bb * 3136 + t) * 16 + co;
    s += psum[pi];
    s2 += psumsq[pi];
  }
  block_reduce2(s, s2);
  if (tid == 0) {
    const float inv = 1.f / 1254400.f;
    float mu = s * inv;
    float var = s2 * inv - mu * mu;
    stats[g * 2] = mu;
    stats[g * 2 + 1] = rsqrtf(var + 1e-5f);
  }
}

__global__ __launch_bounds__(256) void conv_apply_kernel(
    __hip_bfloat16* __restrict__ ra, const __hip_bfloat16* __restrict__ u,
    const float* __restrict__ stats) {
  const int total8 = 5017600;         // 40,140,800 / 8
  int stride = gridDim.x * 256;
  for (int i = blockIdx.x * 256 + threadIdx.x; i < total8; i += stride) {
    int g = i / 156800;               // 1,254,400 / 8 per (b,ch) group
    float mu = stats[g * 2], rstd = stats[g * 2 + 1];
    ushort8 uu = reinterpret_cast<const ushort8*>(u)[i];
    ushort8 rr = reinterpret_cast<const ushort8*>(ra)[i];
    ushort8 oo;
#pragma unroll
    for (int j = 0; j < 8; j++) {
      float rv = bf2f(rr[j]) + gelu_f((bf2f(uu[j]) - mu) * rstd);
      oo[j] = f2bf(rv);
    }
    reinterpret_cast<ushort8*>(ra)[i] = oo;
  }
}

// ---------------- fused MFMA attention (FUSE=1: P1 = ra + gelu(norm(u)) on the fly) ----------------
// LDS 18,944 B -> 8 blocks/CU (32-wave HW cap). rvT and K read as MFMA fragments DIRECTLY
// from global. XCD-chunked blk: the 16 head-blocks of a window share the kv tile -> same-XCD L2.
template <int FUSE>
__global__ __launch_bounds__(256, 8) void attn_kernel(
    const __hip_bfloat16* __restrict__ ra_, const __hip_bfloat16* __restrict__ u_,
    const float* __restrict__ stats, const unsigned short* __restrict__ refvT,
    const __hip_bfloat16* __restrict__ kv_, const unsigned short* __restrict__ rpbT,
    const unsigned short* __restrict__ maskB, __hip_bfloat16* __restrict__ att_) {
  __shared__ __align__(16) char smem[18944];
  unsigned short* P1 = (unsigned short*)smem;              // A: stride 136, rows 0..48 staged
  unsigned short* P2 = (unsigned short*)smem;              // B: stride 72, rows 0..63
  unsigned short* vT = (unsigned short*)(smem + 9216);     // B: stride 72, 32 rows
  unsigned short* qn = (unsigned short*)(smem + 13824);    // stride 40, 64 rows; cols 32..33 lsum

#define LSUM(n) (*reinterpret_cast<float*>(&qn[(n) * 40 + 32]))

  int bid = blockIdx.x;               // 8192 (%8==0 -> bijective chunking)
  int blk = (bid & 7) * 1024 + (bid >> 3);
  int b_ = blk >> 4, h = blk & 15;
  int rb = b_ >> 8, win = b_ & 255;
  int tid = threadIdx.x;
  int wave = tid >> 6, lane = tid & 63;
  int lrow = lane & 15, kq = lane >> 4;
  const unsigned short* ra = (const unsigned short*)ra_;
  const unsigned short* ug = (const unsigned short*)u_;
  const unsigned short* kv = (const unsigned short*)kv_;
  unsigned short* att = (unsigned short*)att_;
  u32x2 zz = {};

  if (tid < 64) LSUM(tid) = 1.0f;
  float mu = 0.f, rstd = 0.f;
  if (FUSE) { mu = stats[(rb * 16 + h) * 2]; rstd = stats[(rb * 16 + h) * 2 + 1]; }

  const size_t tile_off = ((size_t)(rb * 16 + h) * 12544 + win * 49) * 100;
  const unsigned short* rab = ra + tile_off;
  const unsigned short* uab = ug + tile_off;
  for (int i = tid; i < 1225; i += 256) {
    int n = i / 25, c = i % 25;
    u32x2 rv = *reinterpret_cast<const u32x2*>(&rab[n * 100 + c * 4]);
    if (FUSE) {
      u32x2 uv = *reinterpret_cast<const u32x2*>(&uab[n * 100 + c * 4]);
      unsigned short rr4[4] = {(unsigned short)(rv[0] & 0xffff), (unsigned short)(rv[0] >> 16),
                               (unsigned short)(rv[1] & 0xffff), (unsigned short)(rv[1] >> 16)};
      unsigned short uu4[4] = {(unsigned short)(uv[0] & 0xffff), (unsigned short)(uv[0] >> 16),
                               (unsigned short)(uv[1] & 0xffff), (unsigned short)(uv[1] >> 16)};
      unsigned short o4[4];
#pragma unroll
      for (int j = 0; j < 4; j++)
        o4[j] = f2bf(bf2f(rr4[j]) + gelu_f((bf2f(uu4[j]) - mu) * rstd));
      u32x2 w;
      w[0] = (unsigned int)o4[0] | ((unsigned int)o4[1] << 16);
      w[1] = (unsigned int)o4[2] | ((unsigned int)o4[3] << 16);
      *reinterpret_cast<u32x2*>(&P1[n * 136 + c * 4]) = w;
    } else {
      *reinterpret_cast<u32x2*>(&P1[n * 136 + c * 4]) = rv;
    }
  }
  for (int i = tid; i < 343; i += 256) {
    int n = i / 7, c = i % 7;
    *reinterpret_cast<u32x2*>(&P1[n * 136 + 100 + c * 4]) = zz;
  }
  __syncthreads();

  // ---- register softmax over 100 ref slots; store raw e, defer 1/l to qn epilogue ----
  if (tid < 196) {
    int n = tid >> 2, q = tid & 3;
    unsigned short* row = P1 + n * 136 + q * 25;
    float e[25];
#pragma unroll
    for (int r = 0; r < 25; r++) e[r] = bf2f(row[r]);
    float mx = -1e30f;
#pragma unroll
    for (int r = 0; r < 25; r++) mx = fmaxf(mx, e[r]);
    mx = fmaxf(mx, __shfl_xor(mx, 1));
    mx = fmaxf(mx, __shfl_xor(mx, 2));
    float sm = 0.f;
#pragma unroll
    for (int r = 0; r < 25; r++) { e[r] = __expf(e[r] - mx); sm += e[r]; }
    sm += __shfl_xor(sm, 1);
    sm += __shfl_xor(sm, 2);
#pragma unroll
    for (int r = 0; r < 25; r++) row[r] = f2bf(e[r]);
    if (q == 0) LSUM(n) = sm;
  }
  __syncthreads();

  // ---- qnew = P1 @ rvT^T  (M=64, N=32, K=128); rvT fragments direct from global ----
  const unsigned short* rvtg = refvT + (size_t)(rb * 16 + h) * 4096;   // 32 x 128, zero-padded
  f32x4 acc1[2] = {};
#pragma unroll
  for (int ks = 0; ks < 4; ks++) {
    short8 a = *reinterpret_cast<const short8*>(&P1[(wave * 16 + lrow) * 136 + ks * 32 + kq * 8]);
#pragma unroll
    for (int dt = 0; dt < 2; dt++) {
      short8 b = *reinterpret_cast<const short8*>(&rvtg[(dt * 16 + lrow) * 128 + ks * 32 + kq * 8]);
      acc1[dt] = __builtin_amdgcn_mfma_f32_16x16x32_bf16(a, b, acc1[dt], 0, 0, 0);
    }
  }
  float invl[4];
#pragma unroll
  for (int r = 0; r < 4; r++)
    invl[r] = 0.17677669529663688f / LSUM(wave * 16 + kq * 4 + r);
#pragma unroll
  for (int dt = 0; dt < 2; dt++)
#pragma unroll
    for (int r = 0; r < 4; r++) {
      int n = wave * 16 + kq * 4 + r;
      qn[n * 40 + dt * 16 + lrow] = f2bf(acc1[dt][r] * invl[r]);
    }
  __syncthreads();

  // ---- phase B: stage v^T (register transpose) into dead P1 space ----
  const unsigned short* kvb = kv + (size_t)b_ * 49 * 1024;
  for (int i = tid; i < 196; i += 256) {
    int m = i >> 2, dg = (i & 3) * 8;
    ushort8 vv = *reinterpret_cast<const ushort8*>(&kvb[m * 1024 + 512 + h * 32 + dg]);
#pragma unroll
    for (int j = 0; j < 8; j++) vT[(dg + j) * 72 + m] = vv[j];
  }
  for (int i = tid; i < 480; i += 256) vT[(i / 15) * 72 + 49 + i % 15] = 0;
  __syncthreads();

  // ---- logits = qn @ K^T (N=64, K=32); K fragments direct from global; +rpb+mask; softmax ----
  const unsigned short* bt = maskB + (size_t)win * 2744;
  const unsigned short* rt = rpbT + (size_t)h * 2744;
  short8 aq = *reinterpret_cast<const short8*>(&qn[(wave * 16 + lrow) * 40 + kq * 8]);
  f32x4 zero = {};
  float val[4][4];
#pragma unroll
  for (int mt = 0; mt < 4; mt++) {
    int mrow = mt * 16 + lrow;
    int mc = mrow < 49 ? mrow : 48;           // clamp: garbage masked below, stays in-buffer
    short8 bk = *reinterpret_cast<const short8*>(&kvb[mc * 1024 + h * 32 + kq * 8]);
    f32x4 lg = __builtin_amdgcn_mfma_f32_16x16x32_bf16(aq, bk, zero, 0, 0, 0);
    int m = mrow;
#pragma unroll
    for (int r = 0; r < 4; r++) {
      int n = wave * 16 + kq * 4 + r;
      float v;
      if (m < 49 && n < 49)
        v = lg[r] + bf2f(rt[n * 56 + m]) + bf2f(bt[n * 56 + m]);
      else v = -1e30f;
      val[mt][r] = v;
    }
  }
#pragma unroll
  for (int r = 0; r < 4; r++) {
    float mx = -1e30f;
#pragma unroll
    for (int mt = 0; mt < 4; mt++) mx = fmaxf(mx, val[mt][r]);
    mx = fmaxf(mx, __shfl_xor(mx, 1)); mx = fmaxf(mx, __shfl_xor(mx, 2));
    mx = fmaxf(mx, __shfl_xor(mx, 4)); mx = fmaxf(mx, __shfl_xor(mx, 8));
    float sm = 0.f, e[4];
#pragma unroll
    for (int mt = 0; mt < 4; mt++) { e[mt] = __expf(val[mt][r] - mx); sm += e[mt]; }
    sm += __shfl_xor(sm, 1); sm += __shfl_xor(sm, 2);
    sm += __shfl_xor(sm, 4); sm += __shfl_xor(sm, 8);
    float inv = 1.f / sm;
    int n = wave * 16 + kq * 4 + r;
#pragma unroll
    for (int mt = 0; mt < 4; mt++) P2[n * 72 + mt * 16 + lrow] = f2bf(e[mt] * inv);
  }
  __syncthreads();

  // ---- out = P2 @ vT^T (N=32, K=64) -> global bf16 ----
  f32x4 acc2[2] = {};
#pragma unroll
  for (int ks = 0; ks < 2; ks++) {
    short8 ap = *reinterpret_cast<const short8*>(&P2[(wave * 16 + lrow) * 72 + ks * 32 + kq * 8]);
#pragma unroll
    for (int dt = 0; dt < 2; dt++) {
      short8 bv = *reinterpret_cast<const short8*>(&vT[(dt * 16 + lrow) * 72 + ks * 32 + kq * 8]);
      acc2[dt] = __builtin_amdgcn_mfma_f32_16x16x32_bf16(ap, bv, acc2[dt], 0, 0, 0);
    }
  }
  unsigned short* ab = att + (size_t)b_ * 49 * 512 + h * 32;
#pragma unroll
  for (int dt = 0; dt < 2; dt++)
#pragma unroll
    for (int r = 0; r < 4; r++) {
      int n = wave * 16 + kq * 4 + r;
      if (n < 49) ab[n * 512 + dt * 16 + lrow] = f2bf(acc2[dt][r]);
    }
#undef LSUM
}

// ---------------- window-reverse gather + residual + LN2 (wave-per-row) ----------------
__global__ __launch_bounds__(256) void resid_ln2_kernel(
    const float* __restrict__ x, const __hip_bfloat16* __restrict__ proj_out,
    const float* __restrict__ w2, const float* __restrict__ b2,
    float* __restrict__ out, __hip_bfloat16* __restrict__ hout) {
  int tid = threadIdx.x;
  int wave = tid >> 6, lane = tid & 63;
  int blk = blockIdx.x * 4 + wave;    // b*12544 + l
  int bb = blk / 12544, l = blk % 12544;
  int hh = l / 112, ww = l % 112;
  int hs = (hh + 109) % 112, wsx = (ww + 109) % 112;   // (h-3) mod 112
  int t = (bb * 256 + (hs / 7) * 16 + (wsx / 7)) * 49 + (hs % 7) * 7 + (wsx % 7);
  const float* xr = x + (size_t)blk * 512 + lane * 8;
  const unsigned short* pr = (const unsigned short*)proj_out + (size_t)t * 512 + lane * 8;
  f32x4 x0 = *reinterpret_cast<const f32x4*>(xr);
  f32x4 x1 = *reinterpret_cast<const f32x4*>(xr + 4);
  ushort8 p8 = *reinterpret_cast<const ushort8*>(pr);
  float v[8];
#pragma unroll
  for (int j = 0; j < 4; j++) {
    v[j]     = x0[j] + bf2f(p8[j]);
    v[4 + j] = x1[j] + bf2f(p8[4 + j]);
  }
  float s = 0.f, s2 = 0.f;
#pragma unroll
  for (int j = 0; j < 8; j++) { s += v[j]; s2 += v[j] * v[j]; }
  float* orow = out + (size_t)blk * 512 + lane * 8;
  f32x4 o0, o1;
#pragma unroll
  for (int j = 0; j < 4; j++) { o0[j] = v[j]; o1[j] = v[4 + j]; }
  *reinterpret_cast<f32x4*>(orow) = o0;
  *reinterpret_cast<f32x4*>(orow + 4) = o1;
#pragma unroll
  for (int o = 1; o < 64; o <<= 1) { s += __shfl_xor(s, o); s2 += __shfl_xor(s2, o); }
  float mu = s * (1.f / 512.f);
  float rstd = rsqrtf(s2 * (1.f / 512.f) - mu * mu + 1e-5f);
  f32x4 w0 = *reinterpret_cast<const f32x4*>(&w2[lane * 8]);
  f32x4 w1 = *reinterpret_cast<const f32x4*>(&w2[lane * 8 + 4]);
  f32x4 c0 = *reinterpret_cast<const f32x4*>(&b2[lane * 8]);
  f32x4 c1 = *reinterpret_cast<const f32x4*>(&b2[lane * 8 + 4]);
  ushort8 h8;
#pragma unroll
  for (int j = 0; j < 4; j++) {
    h8[j]     = f2bf((v[j] - mu) * rstd * w0[j] + c0[j]);
    h8[4 + j] = f2bf((v[4 + j] - mu) * rstd * w1[j] + c1[j]);
  }
  *reinterpret_cast<ushort8*>((unsigned short*)hout + (size_t)blk * 512 + lane * 8) = h8;
}

// =======================================================================
extern "C" void kernel_launch(void* const* d_in, const int* in_sizes, int n_in,
                              void* d_out, int out_size, void* d_ws, size_t ws_size,
                              hipStream_t stream) {
  const float* x       = (const float*)d_in[0];
  const float* x_ref   = (const float*)d_in[1];
  const float* mask    = (const float*)d_in[2];
  const float* n1w     = (const float*)d_in[3];
  const float* n1b     = (const float*)d_in[4];
  const float* qkv_w   = (const float*)d_in[5];
  const float* qkv_b   = (const float*)d_in[6];
  const float* diff_mu = (const float*)d_in[7];
  const float* diff_ls = (const float*)d_in[8];
  const float* rpb     = (const float*)d_in[9];
  const float* ref_w   = (const float*)d_in[10];
  const float* ref_b   = (const float*)d_in[11];
  const float* conv_w  = (const float*)d_in[12];
  const float* conv_b  = (const float*)d_in[13];
  const float* proj_w  = (const float*)d_in[14];
  const float* proj_b  = (const float*)d_in[15];
  const float* n2w     = (const float*)d_in[16];
  const float* n2b     = (const float*)d_in[17];
  const float* fc1_w   = (const float*)d_in[18];
  const float* fc1_b   = (const float*)d_in[19];
  const float* fc2_w   = (const float*)d_in[20];
  const float* fc2_b   = (const float*)d_in[21];
  float* out = (float*)d_out;

  char* ws = (char*)d_ws;
  size_t off = 0;
  auto alloc = [&](size_t bytes) -> char* {
    char* p = ws + off;
    off += (bytes + 255) & ~(size_t)255;
    return p;
  };
  // ---- persistent small buffers ----
  __hip_bfloat16* wq_bf = (__hip_bfloat16*)alloc(1536ULL * 512 * 2);   // q rows 0..511, kv rows 512..1535
  __hip_bfloat16* wp_bf = (__hip_bfloat16*)alloc(512ULL * 512 * 2);
  __hip_bfloat16* w1_bf = (__hip_bfloat16*)alloc(2048ULL * 512 * 2);
  __hip_bfloat16* w2_bf = (__hip_bfloat16*)alloc(512ULL * 2048 * 2);
  unsigned short* refq  = (unsigned short*)alloc(2ULL * 16 * 100 * 32 * 2);
  unsigned short* refvT = (unsigned short*)alloc(2ULL * 16 * 32 * 128 * 2);  // stride-128 padded
  unsigned short* maskB = (unsigned short*)alloc(256ULL * 49 * 56 * 2);
  unsigned short* rpbT  = (unsigned short*)alloc(16ULL * 49 * 56 * 2);
  unsigned short* cwT   = (unsigned short*)alloc(2560ULL * 2);            // conv weight fragments
  float* psum  = (float*)alloc(2ULL * 3136 * 16 * 4);
  float* psumq = (float*)alloc(2ULL * 3136 * 16 * 4);
  float* stats = (float*)alloc(64 * 4);
  // ---- aliased regions ----
  char* regX  = alloc(25088ULL * 512 * 2);      // xw_bf -> att_bf            (25.7 MB)
  char* regQ  = alloc(25088ULL * 512 * 2);      // q_bf  -> h_bf              (25.7 MB)
  char* regRA = alloc(2ULL * 16 * 12544 * 100 * 2);  // ra    -> hg (per-chunk) (80.3 MB)
  char* regU  = alloc(2ULL * 16 * 12544 * 100 * 2);  // u -> (kv_bf) + proj_bf  (80.3 MB)

  __hip_bfloat16* xw_bf   = (__hip_bfloat16*)regX;
  __hip_bfloat16* att_bf  = (__hip_bfloat16*)regX;                      // after attn
  __hip_bfloat16* q_bf    = (__hip_bfloat16*)regQ;
  __hip_bfloat16* h_bf    = (__hip_bfloat16*)regQ;                      // after ra_kernel
  __hip_bfloat16* ra      = (__hip_bfloat16*)regRA;
  __hip_bfloat16* hg      = (__hip_bfloat16*)regRA;                     // after attn (51.4MB/chunk)
  __hip_bfloat16* u       = (__hip_bfloat16*)regU;
  __hip_bfloat16* proj_bf = (__hip_bfloat16*)(regU + 51380224);         // after attn (25.7MB)

  // fused path needs u live through attn -> kv in a dedicated region if ws allows
  const size_t kv_bytes = 25088ULL * 1024 * 2;   // 51.4 MB
  bool fused = (ws_size >= off + kv_bytes);
  __hip_bfloat16* kv_bf = fused ? (__hip_bfloat16*)alloc(kv_bytes)
                                : (__hip_bfloat16*)regU;   // classic: aliases dead u

  // 1. weights -> bf16 (single vectorized dispatch) ; bias tables
  f2b_all_kernel<<<1536, 256, 0, stream>>>(qkv_w, proj_w, fc1_w, fc2_w,
                                           wq_bf, wp_bf, w1_bf, w2_bf);
  maskb_kernel<<<2744, 256, 0, stream>>>(mask, maskB);
  rpbt_kernel<<<172, 256, 0, stream>>>(rpb, rpbT);
  cwt_kernel<<<10, 256, 0, stream>>>(conv_w, cwT);
  // 2. LN1 + shift + window partition (wave-per-row)
  ln1_window_kernel<<<6272, 256, 0, stream>>>(x, n1w, n1b, xw_bf);
  // 3. q/kv projection (64x128-tile GEMM; grid = (M/64)*(N/128))
  if (fused) {
    // merged qkv GEMM: one A staging pass, outputs routed to q_bf / kv_bf (layouts unchanged)
    gemm_bt<4><<<4704, 256, 0, stream>>>(xw_bf, wq_bf, qkv_b, (float*)kv_bf, q_bf,
                                         25088, 1536, 512);
  } else {
    gemm_bt<1><<<1568, 256, 0, stream>>>(xw_bf, wq_bf, qkv_b, nullptr, q_bf,
                                         25088, 512, 512);
  }
  // 4. reference tokens
  ref_kernel<<<200, 256, 0, stream>>>(x_ref, ref_w, ref_b, diff_mu, diff_ls, refq, refvT);
  // 5. ra = q @ ref_q^T (MFMA, XCD-chunked)
  ra_kernel<<<8192, 256, 0, stream>>>(q_bf, refq, ra);
  // 6. conv diffusion x3 (apply of round 3 folded into attn when fused)
  for (int rd = 0; rd < 3; rd++) {
    conv_kernel<<<dim3(3136, 2), 256, 0, stream>>>(ra, cwT, conv_b, u, psum, psumq);
    conv_stats_kernel<<<32, 256, 0, stream>>>(psum, psumq, stats);
    if (rd < 2 || !fused)
      conv_apply_kernel<<<4096, 256, 0, stream>>>(ra, u, stats);
  }
  // 7. classic path: kv GEMM into dead-u alias (fused path did it in step 3)
  if (!fused)
    gemm_bt<1><<<3136, 256, 0, stream>>>(xw_bf, wq_bf + 512 * 512, qkv_b + 512,
                                         nullptr, kv_bf, 25088, 1024, 512);
  // 8. fused MFMA attention (xw dead -> att_bf; XCD-chunked)
  if (fused)
    attn_kernel<1><<<8192, 256, 0, stream>>>(ra, u, stats, refvT, kv_bf, rpbT, maskB, att_bf);
  else
    attn_kernel<0><<<8192, 256, 0, stream>>>(ra, u, stats, refvT, kv_bf, rpbT, maskB, att_bf);
  // 9. proj GEMM (bias -> bf16, into regU tail; u dead after attn)
  gemm_bt<1><<<1568, 256, 0, stream>>>(att_bf, wp_bf, proj_b, nullptr, proj_bf,
                                       25088, 512, 512);
  // 10. window reverse + residual + LN2 (wave-per-row; h_bf into dead q region)
  resid_ln2_kernel<<<6272, 256, 0, stream>>>(x, proj_bf, n2w, n2b, out, h_bf);
  // 11. MLP in two M-chunks; hg reuses dead ra region
  for (int ch = 0; ch < 2; ch++) {
    const __hip_bfloat16* hA = h_bf + (size_t)ch * 12544 * 512;
    gemm_bt<2><<<3136, 256, 0, stream>>>(hA, w1_bf, fc1_b, nullptr, hg,
                                         12544, 2048, 512);
    gemm_bt<3><<<784, 256, 0, stream>>>(hg, w2_bf, fc2_b,
                                        out + (size_t)ch * 12544 * 512, nullptr,
                                        12544, 512, 2048);
  }
}